// Round 1
// baseline (2751.537 us; speedup 1.0000x reference)
//
#include <hip/hip_runtime.h>
#include <math.h>

#define NN 100000   // nodes
#define NE 640000   // edges
#define DF 128      // in/hidden feat
#define DOUT 40     // out feat

// ---------------------------------------------------------------------------
// ws layout (floats): agg[NN*DF] | cnt[NN] | h[NN*DF]   (~103 MB)
// ---------------------------------------------------------------------------

__device__ __forceinline__ void atomAddF(float* p, float v) {
    unsafeAtomicAdd(p, v);   // native global_atomic_add_f32 on gfx950
}

__global__ __launch_bounds__(256) void count_kernel(const int* __restrict__ dst,
                                                    float* __restrict__ cnt) {
    int e = blockIdx.x * blockDim.x + threadIdx.x;
    if (e < NE) atomAddF(&cnt[dst[e]], 1.0f);
}

__global__ __launch_bounds__(256) void invcnt_kernel(float* __restrict__ cnt) {
    int i = blockIdx.x * blockDim.x + threadIdx.x;
    if (i < NN) cnt[i] = 1.0f / fmaxf(cnt[i], 1.0f);
}

// one thread per (edge, 4-feature chunk): 32 chunks cover 128 feats
__global__ __launch_bounds__(256) void scatter_kernel(const float* __restrict__ feat,
                                                      const int* __restrict__ src,
                                                      const int* __restrict__ dst,
                                                      float* __restrict__ agg) {
    int gid = blockIdx.x * blockDim.x + threadIdx.x;
    int e = gid >> 5;
    int q = gid & 31;
    if (e >= NE) return;
    int s = src[e];
    int d = dst[e];
    const float4 v = *reinterpret_cast<const float4*>(&feat[(size_t)s * DF + q * 4]);
    float* o = &agg[(size_t)d * DF + q * 4];
    atomAddF(&o[0], v.x);
    atomAddF(&o[1], v.y);
    atomAddF(&o[2], v.z);
    atomAddF(&o[3], v.w);
}

// h = relu( (agg*cinv) @ W1l + x @ W1r + b1 ),  [NN,128]
// block: 256 threads, 16 rows; thread -> (r = t>>4, c0 = (t&15)*8)
#define G1_ROWS 16
__global__ __launch_bounds__(256) void gemm1_kernel(const float* __restrict__ x,
                                                    const float* __restrict__ agg,
                                                    const float* __restrict__ cinv,
                                                    const float* __restrict__ W1l,
                                                    const float* __restrict__ W1r,
                                                    const float* __restrict__ b1,
                                                    float* __restrict__ h) {
    __shared__ float sA[G1_ROWS][DF + 4];   // +4 pad: bank-spread rows, keep 16B align
    __shared__ float sX[G1_ROWS][DF + 4];
    __shared__ float sWl[32][DF];
    __shared__ float sWr[32][DF];

    const int t = threadIdx.x;
    const int row0 = blockIdx.x * G1_ROWS;

    // stage 16 rows of scaled-agg and x (float4 granularity: 512 float4 / buffer)
    for (int f = t; f < G1_ROWS * 32; f += 256) {
        int r  = f >> 5;
        int c4 = (f & 31) * 4;
        float sc = cinv[row0 + r];
        float4 av = *reinterpret_cast<const float4*>(&agg[(size_t)(row0 + r) * DF + c4]);
        av.x *= sc; av.y *= sc; av.z *= sc; av.w *= sc;
        *reinterpret_cast<float4*>(&sA[r][c4]) = av;
        *reinterpret_cast<float4*>(&sX[r][c4]) =
            *reinterpret_cast<const float4*>(&x[(size_t)(row0 + r) * DF + c4]);
    }

    const int r  = t >> 4;
    const int c0 = (t & 15) * 8;
    float acc[8] = {0.f, 0.f, 0.f, 0.f, 0.f, 0.f, 0.f, 0.f};

    for (int kc = 0; kc < 4; ++kc) {
        __syncthreads();   // rows staged / previous W-tile consumed
        for (int f = t; f < 32 * 32; f += 256) {
            int kk = f >> 5;
            int c4 = (f & 31) * 4;
            *reinterpret_cast<float4*>(&sWl[kk][c4]) =
                *reinterpret_cast<const float4*>(&W1l[(size_t)(kc * 32 + kk) * DF + c4]);
            *reinterpret_cast<float4*>(&sWr[kk][c4]) =
                *reinterpret_cast<const float4*>(&W1r[(size_t)(kc * 32 + kk) * DF + c4]);
        }
        __syncthreads();
#pragma unroll
        for (int k = 0; k < 32; ++k) {
            float a  = sA[r][kc * 32 + k];
            float xv = sX[r][kc * 32 + k];
            float4 l0 = *reinterpret_cast<const float4*>(&sWl[k][c0]);
            float4 l1 = *reinterpret_cast<const float4*>(&sWl[k][c0 + 4]);
            float4 w0 = *reinterpret_cast<const float4*>(&sWr[k][c0]);
            float4 w1 = *reinterpret_cast<const float4*>(&sWr[k][c0 + 4]);
            acc[0] += a * l0.x + xv * w0.x;
            acc[1] += a * l0.y + xv * w0.y;
            acc[2] += a * l0.z + xv * w0.z;
            acc[3] += a * l0.w + xv * w0.w;
            acc[4] += a * l1.x + xv * w1.x;
            acc[5] += a * l1.y + xv * w1.y;
            acc[6] += a * l1.z + xv * w1.z;
            acc[7] += a * l1.w + xv * w1.w;
        }
    }

    float4 bb0 = *reinterpret_cast<const float4*>(&b1[c0]);
    float4 bb1 = *reinterpret_cast<const float4*>(&b1[c0 + 4]);
    float4 o0, o1;
    o0.x = fmaxf(acc[0] + bb0.x, 0.f);
    o0.y = fmaxf(acc[1] + bb0.y, 0.f);
    o0.z = fmaxf(acc[2] + bb0.z, 0.f);
    o0.w = fmaxf(acc[3] + bb0.w, 0.f);
    o1.x = fmaxf(acc[4] + bb1.x, 0.f);
    o1.y = fmaxf(acc[5] + bb1.y, 0.f);
    o1.z = fmaxf(acc[6] + bb1.z, 0.f);
    o1.w = fmaxf(acc[7] + bb1.w, 0.f);
    size_t base = (size_t)(row0 + r) * DF + c0;
    *reinterpret_cast<float4*>(&h[base])     = o0;
    *reinterpret_cast<float4*>(&h[base + 4]) = o1;
}

// out = log_softmax( (agg*cinv) @ W2l + h @ W2r + b2 ),  [NN,40]
// block: 256 threads = 4 waves, one row per wave; W2 staged in LDS.
__global__ __launch_bounds__(256) void gemm2_kernel(const float* __restrict__ h,
                                                    const float* __restrict__ agg,
                                                    const float* __restrict__ cinv,
                                                    const float* __restrict__ W2l,
                                                    const float* __restrict__ W2r,
                                                    const float* __restrict__ b2,
                                                    float* __restrict__ out) {
    __shared__ float sWl[DF * DOUT];
    __shared__ float sWr[DF * DOUT];
    __shared__ float sB[DOUT];

    const int t = threadIdx.x;
    for (int i = t; i < DF * DOUT; i += 256) {
        sWl[i] = W2l[i];
        sWr[i] = W2r[i];
    }
    if (t < DOUT) sB[t] = b2[t];
    __syncthreads();

    const int wave = t >> 6;
    const int lane = t & 63;
    const int row  = blockIdx.x * 4 + wave;
    if (row >= NN) return;

    const float* hr = &h[(size_t)row * DF];
    const float* ar = &agg[(size_t)row * DF];
    const float ci  = cinv[row];
    const int   c   = (lane < DOUT) ? lane : (DOUT - 1);   // clamp, no OOB

    float acc = sB[c];
#pragma unroll 4
    for (int k = 0; k < DF; ++k) {
        float av = ar[k] * ci;
        float hv = hr[k];
        acc += av * sWl[k * DOUT + c] + hv * sWr[k * DOUT + c];
    }

    // log_softmax over 40 cols (lanes >= 40 padded)
    float v = (lane < DOUT) ? acc : -INFINITY;
    for (int off = 32; off > 0; off >>= 1) v = fmaxf(v, __shfl_down(v, off));
    float m = __shfl(v, 0);
    float e = (lane < DOUT) ? expf(acc - m) : 0.f;
    float ssum = e;
    for (int off = 32; off > 0; off >>= 1) ssum += __shfl_down(ssum, off);
    float s = __shfl(ssum, 0);
    float res = acc - m - logf(s);
    if (lane < DOUT) out[(size_t)row * DOUT + lane] = res;
}

extern "C" void kernel_launch(void* const* d_in, const int* in_sizes, int n_in,
                              void* d_out, int out_size, void* d_ws, size_t ws_size,
                              hipStream_t stream) {
    const float* x   = (const float*)d_in[0];
    const int*   ei  = (const int*)d_in[1];
    const int*   src = ei;
    const int*   dst = ei + NE;
    const float* W1l = (const float*)d_in[2];
    const float* W1r = (const float*)d_in[3];
    const float* b1  = (const float*)d_in[4];
    const float* W2l = (const float*)d_in[5];
    const float* W2r = (const float*)d_in[6];
    const float* b2  = (const float*)d_in[7];
    float* out = (float*)d_out;

    float* agg = (float*)d_ws;
    float* cnt = agg + (size_t)NN * DF;
    float* h   = cnt + NN;

    // zero agg + cnt (contiguous)
    hipMemsetAsync(agg, 0, ((size_t)NN * DF + NN) * sizeof(float), stream);

    count_kernel<<<(NE + 255) / 256, 256, 0, stream>>>(dst, cnt);
    invcnt_kernel<<<(NN + 255) / 256, 256, 0, stream>>>(cnt);

    scatter_kernel<<<(NE * 32) / 256, 256, 0, stream>>>(x, src, dst, agg);
    gemm1_kernel<<<NN / G1_ROWS, 256, 0, stream>>>(x, agg, cnt, W1l, W1r, b1, h);

    hipMemsetAsync(agg, 0, (size_t)NN * DF * sizeof(float), stream);
    scatter_kernel<<<(NE * 32) / 256, 256, 0, stream>>>(h, src, dst, agg);
    gemm2_kernel<<<NN / 4, 256, 0, stream>>>(h, agg, cnt, W2l, W2r, b2, out);
}

// Round 2
// 753.534 us; speedup vs baseline: 3.6515x; 3.6515x over previous
//
#include <hip/hip_runtime.h>
#include <math.h>

#define NN 100000   // nodes
#define NE 640000   // edges
#define DF 128      // in/hidden feat
#define DOUT 40     // out feat

// ---------------------------------------------------------------------------
// ws layout:
//   ints:   deg[NN] | ofs[NN+1] | cur[NN] | srcs[NE] | part[512] | part2[512]
//   floats: agg[NN*DF] | h[NN*DF]
// ---------------------------------------------------------------------------

// ---------------- CSR build ----------------

__global__ __launch_bounds__(256) void hist_kernel(const int* __restrict__ dst,
                                                   int* __restrict__ deg) {
    int e = blockIdx.x * blockDim.x + threadIdx.x;
    if (e < NE) atomicAdd(&deg[dst[e]], 1);
}

// per-block exclusive scan of deg -> ofs(local), block sums -> part
__global__ __launch_bounds__(256) void scan_block_kernel(const int* __restrict__ deg,
                                                         int* __restrict__ ofs,
                                                         int* __restrict__ part) {
    __shared__ int tmp[256];
    const int t = threadIdx.x;
    const int i = blockIdx.x * 256 + t;
    int v = (i < NN) ? deg[i] : 0;
    tmp[t] = v;
    __syncthreads();
    for (int off = 1; off < 256; off <<= 1) {
        int a = (t >= off) ? tmp[t - off] : 0;
        __syncthreads();
        tmp[t] += a;
        __syncthreads();
    }
    if (i < NN) ofs[i] = tmp[t] - v;   // exclusive within block
    if (t == 255) part[blockIdx.x] = tmp[t];
}

// single-block exclusive scan of part[nb] -> part2
__global__ __launch_bounds__(512) void scan_part_kernel(const int* __restrict__ part,
                                                        int* __restrict__ part2,
                                                        int nb) {
    __shared__ int tmp[512];
    const int t = threadIdx.x;
    int v = (t < nb) ? part[t] : 0;
    tmp[t] = v;
    __syncthreads();
    for (int off = 1; off < 512; off <<= 1) {
        int a = (t >= off) ? tmp[t - off] : 0;
        __syncthreads();
        tmp[t] += a;
        __syncthreads();
    }
    if (t < nb) part2[t] = tmp[t] - v;
}

// finalize ofs (add block offsets), ofs[NN]=NE, cursor=ofs
__global__ __launch_bounds__(256) void add_off_kernel(int* __restrict__ ofs,
                                                      const int* __restrict__ part2,
                                                      int* __restrict__ cur) {
    int i = blockIdx.x * 256 + threadIdx.x;
    if (i < NN) {
        int o = ofs[i] + part2[i >> 8];
        ofs[i] = o;
        cur[i] = o;
    }
    if (i == 0) ofs[NN] = NE;
}

__global__ __launch_bounds__(256) void fill_kernel(const int* __restrict__ src,
                                                   const int* __restrict__ dst,
                                                   int* __restrict__ cur,
                                                   int* __restrict__ srcs) {
    int e = blockIdx.x * blockDim.x + threadIdx.x;
    if (e < NE) {
        int pos = atomicAdd(&cur[dst[e]], 1);
        srcs[pos] = src[e];
    }
}

// ---------------- gather-mean aggregation ----------------
// one wave per node; lane holds float2 of the 128-dim row
__global__ __launch_bounds__(256) void gather_mean_kernel(const float* __restrict__ feat,
                                                          const int* __restrict__ ofs,
                                                          const int* __restrict__ srcs,
                                                          float* __restrict__ agg) {
    const int gid  = blockIdx.x * 256 + threadIdx.x;
    const int node = gid >> 6;
    const int lane = threadIdx.x & 63;
    if (node >= NN) return;
    const int b = ofs[node];
    const int e = ofs[node + 1];
    const float* fp = feat + lane * 2;
    float ax = 0.f, ay = 0.f;
    for (int j = b; j < e; ++j) {
        int s = srcs[j];
        float2 v = *reinterpret_cast<const float2*>(fp + (size_t)s * DF);
        ax += v.x;
        ay += v.y;
    }
    const float sc = 1.0f / fmaxf((float)(e - b), 1.0f);
    float2 o = make_float2(ax * sc, ay * sc);
    *reinterpret_cast<float2*>(&agg[(size_t)node * DF + lane * 2]) = o;
}

// ---------------- layer GEMMs ----------------

// h = relu( agg @ W1l + x @ W1r + b1 ),  [NN,128]
#define G1_ROWS 16
__global__ __launch_bounds__(256) void gemm1_kernel(const float* __restrict__ x,
                                                    const float* __restrict__ agg,
                                                    const float* __restrict__ W1l,
                                                    const float* __restrict__ W1r,
                                                    const float* __restrict__ b1,
                                                    float* __restrict__ h) {
    __shared__ float sA[G1_ROWS][DF + 4];
    __shared__ float sX[G1_ROWS][DF + 4];
    __shared__ float sWl[32][DF];
    __shared__ float sWr[32][DF];

    const int t = threadIdx.x;
    const int row0 = blockIdx.x * G1_ROWS;

    for (int f = t; f < G1_ROWS * 32; f += 256) {
        int r  = f >> 5;
        int c4 = (f & 31) * 4;
        *reinterpret_cast<float4*>(&sA[r][c4]) =
            *reinterpret_cast<const float4*>(&agg[(size_t)(row0 + r) * DF + c4]);
        *reinterpret_cast<float4*>(&sX[r][c4]) =
            *reinterpret_cast<const float4*>(&x[(size_t)(row0 + r) * DF + c4]);
    }

    const int r  = t >> 4;
    const int c0 = (t & 15) * 8;
    float acc[8] = {0.f, 0.f, 0.f, 0.f, 0.f, 0.f, 0.f, 0.f};

    for (int kc = 0; kc < 4; ++kc) {
        __syncthreads();
        for (int f = t; f < 32 * 32; f += 256) {
            int kk = f >> 5;
            int c4 = (f & 31) * 4;
            *reinterpret_cast<float4*>(&sWl[kk][c4]) =
                *reinterpret_cast<const float4*>(&W1l[(size_t)(kc * 32 + kk) * DF + c4]);
            *reinterpret_cast<float4*>(&sWr[kk][c4]) =
                *reinterpret_cast<const float4*>(&W1r[(size_t)(kc * 32 + kk) * DF + c4]);
        }
        __syncthreads();
#pragma unroll
        for (int k = 0; k < 32; ++k) {
            float a  = sA[r][kc * 32 + k];
            float xv = sX[r][kc * 32 + k];
            float4 l0 = *reinterpret_cast<const float4*>(&sWl[k][c0]);
            float4 l1 = *reinterpret_cast<const float4*>(&sWl[k][c0 + 4]);
            float4 w0 = *reinterpret_cast<const float4*>(&sWr[k][c0]);
            float4 w1 = *reinterpret_cast<const float4*>(&sWr[k][c0 + 4]);
            acc[0] += a * l0.x + xv * w0.x;
            acc[1] += a * l0.y + xv * w0.y;
            acc[2] += a * l0.z + xv * w0.z;
            acc[3] += a * l0.w + xv * w0.w;
            acc[4] += a * l1.x + xv * w1.x;
            acc[5] += a * l1.y + xv * w1.y;
            acc[6] += a * l1.z + xv * w1.z;
            acc[7] += a * l1.w + xv * w1.w;
        }
    }

    float4 bb0 = *reinterpret_cast<const float4*>(&b1[c0]);
    float4 bb1 = *reinterpret_cast<const float4*>(&b1[c0 + 4]);
    float4 o0, o1;
    o0.x = fmaxf(acc[0] + bb0.x, 0.f);
    o0.y = fmaxf(acc[1] + bb0.y, 0.f);
    o0.z = fmaxf(acc[2] + bb0.z, 0.f);
    o0.w = fmaxf(acc[3] + bb0.w, 0.f);
    o1.x = fmaxf(acc[4] + bb1.x, 0.f);
    o1.y = fmaxf(acc[5] + bb1.y, 0.f);
    o1.z = fmaxf(acc[6] + bb1.z, 0.f);
    o1.w = fmaxf(acc[7] + bb1.w, 0.f);
    size_t base = (size_t)(row0 + r) * DF + c0;
    *reinterpret_cast<float4*>(&h[base])     = o0;
    *reinterpret_cast<float4*>(&h[base + 4]) = o1;
}

// out = log_softmax( agg @ W2l + h @ W2r + b2 ),  [NN,40]
__global__ __launch_bounds__(256) void gemm2_kernel(const float* __restrict__ h,
                                                    const float* __restrict__ agg,
                                                    const float* __restrict__ W2l,
                                                    const float* __restrict__ W2r,
                                                    const float* __restrict__ b2,
                                                    float* __restrict__ out) {
    __shared__ float sWl[DF * DOUT];
    __shared__ float sWr[DF * DOUT];
    __shared__ float sB[DOUT];

    const int t = threadIdx.x;
    for (int i = t; i < DF * DOUT; i += 256) {
        sWl[i] = W2l[i];
        sWr[i] = W2r[i];
    }
    if (t < DOUT) sB[t] = b2[t];
    __syncthreads();

    const int wave = t >> 6;
    const int lane = t & 63;
    const int row  = blockIdx.x * 4 + wave;
    if (row >= NN) return;

    const float* hr = &h[(size_t)row * DF];
    const float* ar = &agg[(size_t)row * DF];
    const int   c   = (lane < DOUT) ? lane : (DOUT - 1);

    float acc = sB[c];
#pragma unroll 4
    for (int k = 0; k < DF; ++k) {
        acc += ar[k] * sWl[k * DOUT + c] + hr[k] * sWr[k * DOUT + c];
    }

    float v = (lane < DOUT) ? acc : -INFINITY;
    for (int off = 32; off > 0; off >>= 1) v = fmaxf(v, __shfl_down(v, off));
    float m = __shfl(v, 0);
    float e = (lane < DOUT) ? expf(acc - m) : 0.f;
    float ssum = e;
    for (int off = 32; off > 0; off >>= 1) ssum += __shfl_down(ssum, off);
    float s = __shfl(ssum, 0);
    float res = acc - m - logf(s);
    if (lane < DOUT) out[(size_t)row * DOUT + lane] = res;
}

extern "C" void kernel_launch(void* const* d_in, const int* in_sizes, int n_in,
                              void* d_out, int out_size, void* d_ws, size_t ws_size,
                              hipStream_t stream) {
    const float* x   = (const float*)d_in[0];
    const int*   ei  = (const int*)d_in[1];
    const int*   src = ei;
    const int*   dst = ei + NE;
    const float* W1l = (const float*)d_in[2];
    const float* W1r = (const float*)d_in[3];
    const float* b1  = (const float*)d_in[4];
    const float* W2l = (const float*)d_in[5];
    const float* W2r = (const float*)d_in[6];
    const float* b2  = (const float*)d_in[7];
    float* out = (float*)d_out;

    int* ip    = (int*)d_ws;
    int* deg   = ip;             // NN
    int* ofs   = ip + 100000;    // NN+1
    int* cur   = ip + 200004;    // NN
    int* srcs  = ip + 300004;    // NE
    int* part  = ip + 940004;    // 512
    int* part2 = ip + 940516;    // 512
    float* agg = (float*)(ip + 941028);        // 16B-aligned
    float* h   = agg + (size_t)NN * DF;

    const int nb = (NN + 255) / 256;  // 391 scan blocks

    hipMemsetAsync(deg, 0, NN * sizeof(int), stream);
    hist_kernel<<<(NE + 255) / 256, 256, 0, stream>>>(dst, deg);
    scan_block_kernel<<<nb, 256, 0, stream>>>(deg, ofs, part);
    scan_part_kernel<<<1, 512, 0, stream>>>(part, part2, nb);
    add_off_kernel<<<nb, 256, 0, stream>>>(ofs, part2, cur);
    fill_kernel<<<(NE + 255) / 256, 256, 0, stream>>>(src, dst, cur, srcs);

    gather_mean_kernel<<<(NN * 64 + 255) / 256, 256, 0, stream>>>(x, ofs, srcs, agg);
    gemm1_kernel<<<NN / G1_ROWS, 256, 0, stream>>>(x, agg, W1l, W1r, b1, h);

    gather_mean_kernel<<<(NN * 64 + 255) / 256, 256, 0, stream>>>(h, ofs, srcs, agg);
    gemm2_kernel<<<NN / 4, 256, 0, stream>>>(h, agg, W2l, W2r, b2, out);
}

// Round 6
// 298.173 us; speedup vs baseline: 9.2280x; 2.5272x over previous
//
#include <hip/hip_runtime.h>
#include <math.h>

#define NN 100000   // nodes
#define NE 640000   // edges
#define DF 128      // in/hidden feat
#define DOUT 40     // out feat

typedef short bf16x8 __attribute__((ext_vector_type(8)));
typedef float f32x4 __attribute__((ext_vector_type(4)));

__device__ __forceinline__ unsigned short f2bf(float f) {
    unsigned int u = __float_as_uint(f);
    u += 0x7fffu + ((u >> 16) & 1u);   // round-to-nearest-even
    return (unsigned short)(u >> 16);
}

// ---------------- prep: fp32 -> bf16 conversions / weight packing ----------

__global__ __launch_bounds__(256) void convert_x_kernel(const float* __restrict__ x,
                                                        unsigned short* __restrict__ xb) {
    int i = (blockIdx.x * 256 + threadIdx.x) * 8;
    float4 a = *reinterpret_cast<const float4*>(x + i);
    float4 b = *reinterpret_cast<const float4*>(x + i + 4);
    uint4 o;
    o.x = (unsigned)f2bf(a.x) | ((unsigned)f2bf(a.y) << 16);
    o.y = (unsigned)f2bf(a.z) | ((unsigned)f2bf(a.w) << 16);
    o.z = (unsigned)f2bf(b.x) | ((unsigned)f2bf(b.y) << 16);
    o.w = (unsigned)f2bf(b.z) | ((unsigned)f2bf(b.w) << 16);
    *reinterpret_cast<uint4*>(xb + (size_t)i) = o;
}

// B-fragment order for mfma_f32_16x16x32_bf16:
//   frag(kt,ct): lane holds B[k = (lane>>4)*8 + j][col = ct*16 + (lane&15)]
__global__ __launch_bounds__(256) void pack_w1_kernel(const float* __restrict__ W1l,
                                                      const float* __restrict__ W1r,
                                                      unsigned short* __restrict__ w1p) {
    int t = blockIdx.x * 256 + threadIdx.x;   // 4096 = 8kt * 8ct * 64
    int lane = t & 63;
    int ct = (t >> 6) & 7;
    int kt = t >> 9;
    int c  = ct * 16 + (lane & 15);
    int k0 = (kt & 3) * 32 + (lane >> 4) * 8;
    const float* W = (kt < 4) ? W1l : W1r;
    unsigned int o[4];
#pragma unroll
    for (int j = 0; j < 4; ++j) {
        unsigned int lo = f2bf(W[(size_t)(k0 + 2 * j) * DF + c]);
        unsigned int hi = f2bf(W[(size_t)(k0 + 2 * j + 1) * DF + c]);
        o[j] = lo | (hi << 16);
    }
    uint4 v; v.x = o[0]; v.y = o[1]; v.z = o[2]; v.w = o[3];
    *reinterpret_cast<uint4*>(w1p + (size_t)t * 8) = v;
}

// 48 padded cols (3 ct), cols >= 40 zeroed
__global__ __launch_bounds__(256) void pack_w2_kernel(const float* __restrict__ W2l,
                                                      const float* __restrict__ W2r,
                                                      unsigned short* __restrict__ w2p) {
    int t = blockIdx.x * 256 + threadIdx.x;   // 1536 = 8kt * 3ct * 64
    if (t >= 1536) return;
    int lane = t & 63;
    int g  = t >> 6;       // kt*3 + ct
    int ct = g % 3;
    int kt = g / 3;
    int c  = ct * 16 + (lane & 15);
    int k0 = (kt & 3) * 32 + (lane >> 4) * 8;
    const float* W = (kt < 4) ? W2l : W2r;
    unsigned int o[4];
#pragma unroll
    for (int j = 0; j < 4; ++j) {
        unsigned int lo = (c < DOUT) ? f2bf(W[(size_t)(k0 + 2 * j) * DOUT + c]) : 0u;
        unsigned int hi = (c < DOUT) ? f2bf(W[(size_t)(k0 + 2 * j + 1) * DOUT + c]) : 0u;
        o[j] = lo | (hi << 16);
    }
    uint4 v; v.x = o[0]; v.y = o[1]; v.z = o[2]; v.w = o[3];
    *reinterpret_cast<uint4*>(w2p + (size_t)t * 8) = v;
}

// ---------------- CSR build (no SDMA memset; ofs write-once) ----------------

__global__ __launch_bounds__(256) void zero_deg_kernel(int* __restrict__ deg) {
    int i = blockIdx.x * 256 + threadIdx.x;
    if (i < NN) deg[i] = 0;
}

__global__ __launch_bounds__(256) void hist_kernel(const int* __restrict__ dst,
                                                   int* __restrict__ deg) {
    int e = blockIdx.x * blockDim.x + threadIdx.x;
    if (e < NE) atomicAdd(&deg[dst[e]], 1);
}

// per-block exclusive scan of deg -> loc(local), block sums -> part
__global__ __launch_bounds__(256) void scan_block_kernel(const int* __restrict__ deg,
                                                         int* __restrict__ loc,
                                                         int* __restrict__ part) {
    __shared__ int tmp[256];
    const int t = threadIdx.x;
    const int i = blockIdx.x * 256 + t;
    int v = (i < NN) ? deg[i] : 0;
    tmp[t] = v;
    __syncthreads();
    for (int off = 1; off < 256; off <<= 1) {
        int a = (t >= off) ? tmp[t - off] : 0;
        __syncthreads();
        tmp[t] += a;
        __syncthreads();
    }
    if (i < NN) loc[i] = tmp[t] - v;
    if (t == 255) part[blockIdx.x] = tmp[t];
}

__global__ __launch_bounds__(512) void scan_part_kernel(const int* __restrict__ part,
                                                        int* __restrict__ part2,
                                                        int nb) {
    __shared__ int tmp[512];
    const int t = threadIdx.x;
    int v = (t < nb) ? part[t] : 0;
    tmp[t] = v;
    __syncthreads();
    for (int off = 1; off < 512; off <<= 1) {
        int a = (t >= off) ? tmp[t - off] : 0;
        __syncthreads();
        tmp[t] += a;
        __syncthreads();
    }
    if (t < nb) part2[t] = tmp[t] - v;
}

// ofs gets FINAL values only (write-once), cursor = ofs
__global__ __launch_bounds__(256) void add_off_kernel(const int* __restrict__ loc,
                                                      const int* __restrict__ part2,
                                                      int* __restrict__ ofs,
                                                      int* __restrict__ cur) {
    int i = blockIdx.x * 256 + threadIdx.x;
    if (i < NN) {
        int o = loc[i] + part2[i >> 8];
        ofs[i] = o;
        cur[i] = o;
    }
    if (i == 0) ofs[NN] = NE;
}

__global__ __launch_bounds__(256) void fill_kernel(const int* __restrict__ src,
                                                   const int* __restrict__ dst,
                                                   int* __restrict__ cur,
                                                   int* __restrict__ srcs) {
    int e = blockIdx.x * blockDim.x + threadIdx.x;
    if (e < NE) {
        int pos = atomicAdd(&cur[dst[e]], 1);
        srcs[pos] = src[e];
    }
}

// ---------------- gather-mean (bf16 in -> bf16 out) ----------------
// one wave per node; lane holds 2 bf16 of the 128-dim row
__global__ __launch_bounds__(256) void gather_mean_kernel(const unsigned short* __restrict__ feat,
                                                          const int* __restrict__ ofs,
                                                          const int* __restrict__ srcs,
                                                          unsigned short* __restrict__ agg) {
    const int gid  = blockIdx.x * 256 + threadIdx.x;
    const int node = gid >> 6;
    const int lane = threadIdx.x & 63;
    if (node >= NN) return;
    const int b = ofs[node];
    const int e = ofs[node + 1];
    const unsigned short* fp = feat + lane * 2;
    float ax = 0.f, ay = 0.f;
    for (int j = b; j < e; ++j) {
        int s = srcs[j];
        if ((unsigned)s < (unsigned)NN) {   // defensive: no wild reads ever
            unsigned int v = *reinterpret_cast<const unsigned int*>(fp + (size_t)s * DF);
            ax += __uint_as_float(v << 16);
            ay += __uint_as_float(v & 0xffff0000u);
        }
    }
    const float sc = 1.0f / fmaxf((float)(e - b), 1.0f);
    unsigned int o = (unsigned)f2bf(ax * sc) | ((unsigned)f2bf(ay * sc) << 16);
    *reinterpret_cast<unsigned int*>(agg + (size_t)node * DF + lane * 2) = o;
}

// ---------------- MFMA GEMMs ----------------
// A-frag: lane holds A[row = lane&15][k = (lane>>4)*8 + j]
#define G_ROWS 64
#define LDSW 136

__global__ __launch_bounds__(256) void gemm1_kernel(const unsigned short* __restrict__ aggb,
                                                    const unsigned short* __restrict__ xb,
                                                    const unsigned short* __restrict__ w1p,
                                                    const float* __restrict__ b1,
                                                    unsigned short* __restrict__ hb) {
    __shared__ unsigned short sA[G_ROWS * LDSW];
    __shared__ unsigned short sX[G_ROWS * LDSW];
    const int t = threadIdx.x;
    const int row0 = blockIdx.x * G_ROWS;

    for (int i = t; i < G_ROWS * 16; i += 256) {
        int r = i >> 4, ch = i & 15;
        int sr = row0 + r; if (sr > NN - 1) sr = NN - 1;
        *reinterpret_cast<uint4*>(&sA[r * LDSW + ch * 8]) =
            *reinterpret_cast<const uint4*>(aggb + (size_t)sr * DF + ch * 8);
        *reinterpret_cast<uint4*>(&sX[r * LDSW + ch * 8]) =
            *reinterpret_cast<const uint4*>(xb + (size_t)sr * DF + ch * 8);
    }
    __syncthreads();

    const int lane = t & 63;
    const int w = t >> 6;
    const int lr = lane & 15;
    const int hi = lane >> 4;
    f32x4 acc[8];
#pragma unroll
    for (int i = 0; i < 8; ++i) acc[i] = (f32x4){0.f, 0.f, 0.f, 0.f};

    const int arow = (w * 16 + lr) * LDSW + hi * 8;
#pragma unroll
    for (int half = 0; half < 2; ++half) {
        const unsigned short* base = half ? sX : sA;
#pragma unroll
        for (int kq = 0; kq < 4; ++kq) {
            bf16x8 a = __builtin_bit_cast(bf16x8,
                *reinterpret_cast<const uint4*>(&base[arow + kq * 32]));
            const unsigned short* wp = w1p + (size_t)(((half * 4 + kq) * 8) * 64 + lane) * 8;
#pragma unroll
            for (int ct = 0; ct < 8; ++ct) {
                bf16x8 b = __builtin_bit_cast(bf16x8,
                    *reinterpret_cast<const uint4*>(wp + ct * 512));
                acc[ct] = __builtin_amdgcn_mfma_f32_16x16x32_bf16(a, b, acc[ct], 0, 0, 0);
            }
        }
    }

#pragma unroll
    for (int ct = 0; ct < 8; ++ct) {
        int col = ct * 16 + lr;
        float bias = b1[col];
#pragma unroll
        for (int v = 0; v < 4; ++v) {
            int row = row0 + w * 16 + hi * 4 + v;
            if (row < NN) {
                float o = fmaxf(acc[ct][v] + bias, 0.f);
                hb[(size_t)row * DF + col] = f2bf(o);
            }
        }
    }
}

__global__ __launch_bounds__(256) void gemm2_kernel(const unsigned short* __restrict__ aggb,
                                                    const unsigned short* __restrict__ hb,
                                                    const unsigned short* __restrict__ w2p,
                                                    const float* __restrict__ b2,
                                                    float* __restrict__ out) {
    __shared__ unsigned short sA[G_ROWS * LDSW];
    __shared__ unsigned short sH[G_ROWS * LDSW];
    const int t = threadIdx.x;
    const int row0 = blockIdx.x * G_ROWS;

    for (int i = t; i < G_ROWS * 16; i += 256) {
        int r = i >> 4, ch = i & 15;
        int sr = row0 + r; if (sr > NN - 1) sr = NN - 1;
        *reinterpret_cast<uint4*>(&sA[r * LDSW + ch * 8]) =
            *reinterpret_cast<const uint4*>(aggb + (size_t)sr * DF + ch * 8);
        *reinterpret_cast<uint4*>(&sH[r * LDSW + ch * 8]) =
            *reinterpret_cast<const uint4*>(hb + (size_t)sr * DF + ch * 8);
    }
    __syncthreads();

    const int lane = t & 63;
    const int w = t >> 6;
    const int lr = lane & 15;
    const int hi = lane >> 4;
    f32x4 acc[3];
#pragma unroll
    for (int i = 0; i < 3; ++i) acc[i] = (f32x4){0.f, 0.f, 0.f, 0.f};

    const int arow = (w * 16 + lr) * LDSW + hi * 8;
#pragma unroll
    for (int half = 0; half < 2; ++half) {
        const unsigned short* base = half ? sH : sA;
#pragma unroll
        for (int kq = 0; kq < 4; ++kq) {
            bf16x8 a = __builtin_bit_cast(bf16x8,
                *reinterpret_cast<const uint4*>(&base[arow + kq * 32]));
            const unsigned short* wp = w2p + (size_t)(((half * 4 + kq) * 3) * 64 + lane) * 8;
#pragma unroll
            for (int ct = 0; ct < 3; ++ct) {
                bf16x8 b = __builtin_bit_cast(bf16x8,
                    *reinterpret_cast<const uint4*>(wp + ct * 512));
                acc[ct] = __builtin_amdgcn_mfma_f32_16x16x32_bf16(a, b, acc[ct], 0, 0, 0);
            }
        }
    }

    // bias + log_softmax over 40 cols, per C-fragment row
    const int c = lr;
    float bb0 = b2[c];
    float bb1 = b2[16 + c];
    float bb2 = (c < 8) ? b2[32 + c] : 0.f;

#pragma unroll
    for (int v = 0; v < 4; ++v) {
        float l0 = acc[0][v] + bb0;
        float l1 = acc[1][v] + bb1;
        float l2 = (c < 8) ? (acc[2][v] + bb2) : -INFINITY;
        float mx = fmaxf(fmaxf(l0, l1), l2);
        mx = fmaxf(mx, __shfl_xor(mx, 1));
        mx = fmaxf(mx, __shfl_xor(mx, 2));
        mx = fmaxf(mx, __shfl_xor(mx, 4));
        mx = fmaxf(mx, __shfl_xor(mx, 8));
        float s = __expf(l0 - mx) + __expf(l1 - mx) + ((c < 8) ? __expf(l2 - mx) : 0.f);
        s += __shfl_xor(s, 1);
        s += __shfl_xor(s, 2);
        s += __shfl_xor(s, 4);
        s += __shfl_xor(s, 8);
        float lz = mx + __logf(s);
        int row = row0 + w * 16 + hi * 4 + v;
        if (row < NN) {
            out[(size_t)row * DOUT + c]      = l0 - lz;
            out[(size_t)row * DOUT + 16 + c] = l1 - lz;
            if (c < 8) out[(size_t)row * DOUT + 32 + c] = l2 - lz;
        }
    }
}

extern "C" void kernel_launch(void* const* d_in, const int* in_sizes, int n_in,
                              void* d_out, int out_size, void* d_ws, size_t ws_size,
                              hipStream_t stream) {
    const float* x   = (const float*)d_in[0];
    const int*   ei  = (const int*)d_in[1];
    const int*   src = ei;
    const int*   dst = ei + NE;
    const float* W1l = (const float*)d_in[2];
    const float* W1r = (const float*)d_in[3];
    const float* b1  = (const float*)d_in[4];
    const float* W2l = (const float*)d_in[5];
    const float* W2r = (const float*)d_in[6];
    const float* b2  = (const float*)d_in[7];
    float* out = (float*)d_out;

    int* ip    = (int*)d_ws;
    int* deg   = ip;              // NN
    int* loc   = ip + 100000;     // NN
    int* ofs   = ip + 200000;     // NN+1 (pad to 100004)
    int* cur   = ip + 300004;     // NN
    int* srcs  = ip + 400004;     // NE
    int* part  = ip + 1040004;    // 512
    int* part2 = ip + 1040516;    // 512
    unsigned short* up   = (unsigned short*)(ip + 1041028);  // 16B aligned
    unsigned short* xb   = up;                   // NN*DF
    unsigned short* aggb = up + 12800000;        // NN*DF
    unsigned short* hb   = up + 25600000;        // NN*DF
    unsigned short* w1p  = up + 38400000;        // 32768
    unsigned short* w2p  = up + 38432768;        // 12288

    convert_x_kernel<<<6250, 256, 0, stream>>>(x, xb);
    pack_w1_kernel<<<16, 256, 0, stream>>>(W1l, W1r, w1p);
    pack_w2_kernel<<<6, 256, 0, stream>>>(W2l, W2r, w2p);

    zero_deg_kernel<<<391, 256, 0, stream>>>(deg);
    hist_kernel<<<(NE + 255) / 256, 256, 0, stream>>>(dst, deg);
    scan_block_kernel<<<391, 256, 0, stream>>>(deg, loc, part);
    scan_part_kernel<<<1, 512, 0, stream>>>(part, part2, 391);
    add_off_kernel<<<391, 256, 0, stream>>>(loc, part2, ofs, cur);
    fill_kernel<<<(NE + 255) / 256, 256, 0, stream>>>(src, dst, cur, srcs);

    gather_mean_kernel<<<25000, 256, 0, stream>>>(xb, ofs, srcs, aggb);
    gemm1_kernel<<<1563, 256, 0, stream>>>(aggb, xb, w1p, b1, hb);
    gather_mean_kernel<<<25000, 256, 0, stream>>>(hb, ofs, srcs, aggb);
    gemm2_kernel<<<1563, 256, 0, stream>>>(aggb, hb, w2p, b2, out);
}

// Round 7
// 237.511 us; speedup vs baseline: 11.5849x; 1.2554x over previous
//
#include <hip/hip_runtime.h>
#include <math.h>

#define NN 100000   // nodes
#define NE 640000   // edges
#define DF 128      // in/hidden feat
#define DOUT 40     // out feat

typedef short bf16x8 __attribute__((ext_vector_type(8)));
typedef float f32x4 __attribute__((ext_vector_type(4)));

__device__ __forceinline__ unsigned short f2bf(float f) {
    unsigned int u = __float_as_uint(f);
    u += 0x7fffu + ((u >> 16) & 1u);   // round-to-nearest-even
    return (unsigned short)(u >> 16);
}

// ---------------- prep: fp32 -> bf16 conversions / weight packing ----------

__global__ __launch_bounds__(256) void convert_x_kernel(const float* __restrict__ x,
                                                        unsigned short* __restrict__ xb) {
    int i = (blockIdx.x * 256 + threadIdx.x) * 8;
    float4 a = *reinterpret_cast<const float4*>(x + i);
    float4 b = *reinterpret_cast<const float4*>(x + i + 4);
    uint4 o;
    o.x = (unsigned)f2bf(a.x) | ((unsigned)f2bf(a.y) << 16);
    o.y = (unsigned)f2bf(a.z) | ((unsigned)f2bf(a.w) << 16);
    o.z = (unsigned)f2bf(b.x) | ((unsigned)f2bf(b.y) << 16);
    o.w = (unsigned)f2bf(b.z) | ((unsigned)f2bf(b.w) << 16);
    *reinterpret_cast<uint4*>(xb + (size_t)i) = o;
}

// B-fragment order for mfma_f32_16x16x32_bf16:
//   frag(kt,ct): lane holds B[k = (lane>>4)*8 + j][col = ct*16 + (lane&15)]
__global__ __launch_bounds__(256) void pack_w1_kernel(const float* __restrict__ W1l,
                                                      const float* __restrict__ W1r,
                                                      unsigned short* __restrict__ w1p) {
    int t = blockIdx.x * 256 + threadIdx.x;   // 4096 = 8kt * 8ct * 64
    int lane = t & 63;
    int ct = (t >> 6) & 7;
    int kt = t >> 9;
    int c  = ct * 16 + (lane & 15);
    int k0 = (kt & 3) * 32 + (lane >> 4) * 8;
    const float* W = (kt < 4) ? W1l : W1r;
    unsigned int o[4];
#pragma unroll
    for (int j = 0; j < 4; ++j) {
        unsigned int lo = f2bf(W[(size_t)(k0 + 2 * j) * DF + c]);
        unsigned int hi = f2bf(W[(size_t)(k0 + 2 * j + 1) * DF + c]);
        o[j] = lo | (hi << 16);
    }
    uint4 v; v.x = o[0]; v.y = o[1]; v.z = o[2]; v.w = o[3];
    *reinterpret_cast<uint4*>(w1p + (size_t)t * 8) = v;
}

// 48 padded cols (3 ct), cols >= 40 zeroed
__global__ __launch_bounds__(256) void pack_w2_kernel(const float* __restrict__ W2l,
                                                      const float* __restrict__ W2r,
                                                      unsigned short* __restrict__ w2p) {
    int t = blockIdx.x * 256 + threadIdx.x;   // 1536 = 8kt * 3ct * 64
    if (t >= 1536) return;
    int lane = t & 63;
    int g  = t >> 6;       // kt*3 + ct
    int ct = g % 3;
    int kt = g / 3;
    int c  = ct * 16 + (lane & 15);
    int k0 = (kt & 3) * 32 + (lane >> 4) * 8;
    const float* W = (kt < 4) ? W2l : W2r;
    unsigned int o[4];
#pragma unroll
    for (int j = 0; j < 4; ++j) {
        unsigned int lo = (c < DOUT) ? f2bf(W[(size_t)(k0 + 2 * j) * DOUT + c]) : 0u;
        unsigned int hi = (c < DOUT) ? f2bf(W[(size_t)(k0 + 2 * j + 1) * DOUT + c]) : 0u;
        o[j] = lo | (hi << 16);
    }
    uint4 v; v.x = o[0]; v.y = o[1]; v.z = o[2]; v.w = o[3];
    *reinterpret_cast<uint4*>(w2p + (size_t)t * 8) = v;
}

// ---------------- CSR build (no SDMA memset; ofs write-once) ----------------

__global__ __launch_bounds__(256) void zero_deg_kernel(int* __restrict__ deg) {
    int i = blockIdx.x * 256 + threadIdx.x;
    if (i < NN) deg[i] = 0;
}

__global__ __launch_bounds__(256) void hist_kernel(const int* __restrict__ dst,
                                                   int* __restrict__ deg) {
    int e = blockIdx.x * blockDim.x + threadIdx.x;
    if (e < NE) atomicAdd(&deg[dst[e]], 1);
}

// per-block exclusive scan of deg -> loc(local), block sums -> part
__global__ __launch_bounds__(256) void scan_block_kernel(const int* __restrict__ deg,
                                                         int* __restrict__ loc,
                                                         int* __restrict__ part) {
    __shared__ int tmp[256];
    const int t = threadIdx.x;
    const int i = blockIdx.x * 256 + t;
    int v = (i < NN) ? deg[i] : 0;
    tmp[t] = v;
    __syncthreads();
    for (int off = 1; off < 256; off <<= 1) {
        int a = (t >= off) ? tmp[t - off] : 0;
        __syncthreads();
        tmp[t] += a;
        __syncthreads();
    }
    if (i < NN) loc[i] = tmp[t] - v;
    if (t == 255) part[blockIdx.x] = tmp[t];
}

__global__ __launch_bounds__(512) void scan_part_kernel(const int* __restrict__ part,
                                                        int* __restrict__ part2,
                                                        int nb) {
    __shared__ int tmp[512];
    const int t = threadIdx.x;
    int v = (t < nb) ? part[t] : 0;
    tmp[t] = v;
    __syncthreads();
    for (int off = 1; off < 512; off <<= 1) {
        int a = (t >= off) ? tmp[t - off] : 0;
        __syncthreads();
        tmp[t] += a;
        __syncthreads();
    }
    if (t < nb) part2[t] = tmp[t] - v;
}

// ofs gets FINAL values only (write-once), cursor = ofs
__global__ __launch_bounds__(256) void add_off_kernel(const int* __restrict__ loc,
                                                      const int* __restrict__ part2,
                                                      int* __restrict__ ofs,
                                                      int* __restrict__ cur) {
    int i = blockIdx.x * 256 + threadIdx.x;
    if (i < NN) {
        int o = loc[i] + part2[i >> 8];
        ofs[i] = o;
        cur[i] = o;
    }
    if (i == 0) ofs[NN] = NE;
}

__global__ __launch_bounds__(256) void fill_kernel(const int* __restrict__ src,
                                                   const int* __restrict__ dst,
                                                   int* __restrict__ cur,
                                                   int* __restrict__ srcs) {
    int e = blockIdx.x * blockDim.x + threadIdx.x;
    if (e < NE) {
        int pos = atomicAdd(&cur[dst[e]], 1);
        srcs[pos] = src[e];
    }
}

// ---------------- gather-mean (bf16 in -> bf16 out) ----------------
// one wave per node; lane holds 2 bf16 of the 128-dim row.
// 4-unrolled: 4 independent gather loads in flight per group to hide L2/L3
// latency (the serial 1-load chain was the round-6 bottleneck).
__global__ __launch_bounds__(256) void gather_mean_kernel(const unsigned short* __restrict__ feat,
                                                          const int* __restrict__ ofs,
                                                          const int* __restrict__ srcs,
                                                          unsigned short* __restrict__ agg) {
    const int gid  = blockIdx.x * 256 + threadIdx.x;
    const int node = gid >> 6;
    const int lane = threadIdx.x & 63;
    if (node >= NN) return;
    const int b = ofs[node];
    const int e = ofs[node + 1];
    const unsigned short* fp = feat + lane * 2;

    float ax0 = 0.f, ay0 = 0.f, ax1 = 0.f, ay1 = 0.f;
    float ax2 = 0.f, ay2 = 0.f, ax3 = 0.f, ay3 = 0.f;

    int j = b;
    for (; j + 4 <= e; j += 4) {
        int s0 = srcs[j];
        int s1 = srcs[j + 1];
        int s2 = srcs[j + 2];
        int s3 = srcs[j + 3];
        unsigned int v0 = 0, v1 = 0, v2 = 0, v3 = 0;
        if ((unsigned)s0 < (unsigned)NN) v0 = *reinterpret_cast<const unsigned int*>(fp + (size_t)s0 * DF);
        if ((unsigned)s1 < (unsigned)NN) v1 = *reinterpret_cast<const unsigned int*>(fp + (size_t)s1 * DF);
        if ((unsigned)s2 < (unsigned)NN) v2 = *reinterpret_cast<const unsigned int*>(fp + (size_t)s2 * DF);
        if ((unsigned)s3 < (unsigned)NN) v3 = *reinterpret_cast<const unsigned int*>(fp + (size_t)s3 * DF);
        ax0 += __uint_as_float(v0 << 16);  ay0 += __uint_as_float(v0 & 0xffff0000u);
        ax1 += __uint_as_float(v1 << 16);  ay1 += __uint_as_float(v1 & 0xffff0000u);
        ax2 += __uint_as_float(v2 << 16);  ay2 += __uint_as_float(v2 & 0xffff0000u);
        ax3 += __uint_as_float(v3 << 16);  ay3 += __uint_as_float(v3 & 0xffff0000u);
    }
    for (; j < e; ++j) {
        int s = srcs[j];
        if ((unsigned)s < (unsigned)NN) {
            unsigned int v = *reinterpret_cast<const unsigned int*>(fp + (size_t)s * DF);
            ax0 += __uint_as_float(v << 16);
            ay0 += __uint_as_float(v & 0xffff0000u);
        }
    }

    float ax = (ax0 + ax1) + (ax2 + ax3);
    float ay = (ay0 + ay1) + (ay2 + ay3);
    const float sc = 1.0f / fmaxf((float)(e - b), 1.0f);
    unsigned int o = (unsigned)f2bf(ax * sc) | ((unsigned)f2bf(ay * sc) << 16);
    *reinterpret_cast<unsigned int*>(agg + (size_t)node * DF + lane * 2) = o;
}

// ---------------- MFMA GEMMs ----------------
// A-frag: lane holds A[row = lane&15][k = (lane>>4)*8 + j]
#define G_ROWS 64
#define LDSW 136

__global__ __launch_bounds__(256) void gemm1_kernel(const unsigned short* __restrict__ aggb,
                                                    const unsigned short* __restrict__ xb,
                                                    const unsigned short* __restrict__ w1p,
                                                    const float* __restrict__ b1,
                                                    unsigned short* __restrict__ hb) {
    __shared__ unsigned short sA[G_ROWS * LDSW];
    __shared__ unsigned short sX[G_ROWS * LDSW];
    const int t = threadIdx.x;
    const int row0 = blockIdx.x * G_ROWS;

    for (int i = t; i < G_ROWS * 16; i += 256) {
        int r = i >> 4, ch = i & 15;
        int sr = row0 + r; if (sr > NN - 1) sr = NN - 1;
        *reinterpret_cast<uint4*>(&sA[r * LDSW + ch * 8]) =
            *reinterpret_cast<const uint4*>(aggb + (size_t)sr * DF + ch * 8);
        *reinterpret_cast<uint4*>(&sX[r * LDSW + ch * 8]) =
            *reinterpret_cast<const uint4*>(xb + (size_t)sr * DF + ch * 8);
    }
    __syncthreads();

    const int lane = t & 63;
    const int w = t >> 6;
    const int lr = lane & 15;
    const int hi = lane >> 4;
    f32x4 acc[8];
#pragma unroll
    for (int i = 0; i < 8; ++i) acc[i] = (f32x4){0.f, 0.f, 0.f, 0.f};

    const int arow = (w * 16 + lr) * LDSW + hi * 8;
#pragma unroll
    for (int half = 0; half < 2; ++half) {
        const unsigned short* base = half ? sX : sA;
#pragma unroll
        for (int kq = 0; kq < 4; ++kq) {
            bf16x8 a = __builtin_bit_cast(bf16x8,
                *reinterpret_cast<const uint4*>(&base[arow + kq * 32]));
            const unsigned short* wp = w1p + (size_t)(((half * 4 + kq) * 8) * 64 + lane) * 8;
#pragma unroll
            for (int ct = 0; ct < 8; ++ct) {
                bf16x8 b = __builtin_bit_cast(bf16x8,
                    *reinterpret_cast<const uint4*>(wp + ct * 512));
                acc[ct] = __builtin_amdgcn_mfma_f32_16x16x32_bf16(a, b, acc[ct], 0, 0, 0);
            }
        }
    }

#pragma unroll
    for (int ct = 0; ct < 8; ++ct) {
        int col = ct * 16 + lr;
        float bias = b1[col];
#pragma unroll
        for (int v = 0; v < 4; ++v) {
            int row = row0 + w * 16 + hi * 4 + v;
            if (row < NN) {
                float o = fmaxf(acc[ct][v] + bias, 0.f);
                hb[(size_t)row * DF + col] = f2bf(o);
            }
        }
    }
}

__global__ __launch_bounds__(256) void gemm2_kernel(const unsigned short* __restrict__ aggb,
                                                    const unsigned short* __restrict__ hb,
                                                    const unsigned short* __restrict__ w2p,
                                                    const float* __restrict__ b2,
                                                    float* __restrict__ out) {
    __shared__ unsigned short sA[G_ROWS * LDSW];
    __shared__ unsigned short sH[G_ROWS * LDSW];
    const int t = threadIdx.x;
    const int row0 = blockIdx.x * G_ROWS;

    for (int i = t; i < G_ROWS * 16; i += 256) {
        int r = i >> 4, ch = i & 15;
        int sr = row0 + r; if (sr > NN - 1) sr = NN - 1;
        *reinterpret_cast<uint4*>(&sA[r * LDSW + ch * 8]) =
            *reinterpret_cast<const uint4*>(aggb + (size_t)sr * DF + ch * 8);
        *reinterpret_cast<uint4*>(&sH[r * LDSW + ch * 8]) =
            *reinterpret_cast<const uint4*>(hb + (size_t)sr * DF + ch * 8);
    }
    __syncthreads();

    const int lane = t & 63;
    const int w = t >> 6;
    const int lr = lane & 15;
    const int hi = lane >> 4;
    f32x4 acc[3];
#pragma unroll
    for (int i = 0; i < 3; ++i) acc[i] = (f32x4){0.f, 0.f, 0.f, 0.f};

    const int arow = (w * 16 + lr) * LDSW + hi * 8;
#pragma unroll
    for (int half = 0; half < 2; ++half) {
        const unsigned short* base = half ? sH : sA;
#pragma unroll
        for (int kq = 0; kq < 4; ++kq) {
            bf16x8 a = __builtin_bit_cast(bf16x8,
                *reinterpret_cast<const uint4*>(&base[arow + kq * 32]));
            const unsigned short* wp = w2p + (size_t)(((half * 4 + kq) * 3) * 64 + lane) * 8;
#pragma unroll
            for (int ct = 0; ct < 3; ++ct) {
                bf16x8 b = __builtin_bit_cast(bf16x8,
                    *reinterpret_cast<const uint4*>(wp + ct * 512));
                acc[ct] = __builtin_amdgcn_mfma_f32_16x16x32_bf16(a, b, acc[ct], 0, 0, 0);
            }
        }
    }

    // bias + log_softmax over 40 cols, per C-fragment row
    const int c = lr;
    float bb0 = b2[c];
    float bb1 = b2[16 + c];
    float bb2 = (c < 8) ? b2[32 + c] : 0.f;

#pragma unroll
    for (int v = 0; v < 4; ++v) {
        float l0 = acc[0][v] + bb0;
        float l1 = acc[1][v] + bb1;
        float l2 = (c < 8) ? (acc[2][v] + bb2) : -INFINITY;
        float mx = fmaxf(fmaxf(l0, l1), l2);
        mx = fmaxf(mx, __shfl_xor(mx, 1));
        mx = fmaxf(mx, __shfl_xor(mx, 2));
        mx = fmaxf(mx, __shfl_xor(mx, 4));
        mx = fmaxf(mx, __shfl_xor(mx, 8));
        float s = __expf(l0 - mx) + __expf(l1 - mx) + ((c < 8) ? __expf(l2 - mx) : 0.f);
        s += __shfl_xor(s, 1);
        s += __shfl_xor(s, 2);
        s += __shfl_xor(s, 4);
        s += __shfl_xor(s, 8);
        float lz = mx + __logf(s);
        int row = row0 + w * 16 + hi * 4 + v;
        if (row < NN) {
            out[(size_t)row * DOUT + c]      = l0 - lz;
            out[(size_t)row * DOUT + 16 + c] = l1 - lz;
            if (c < 8) out[(size_t)row * DOUT + 32 + c] = l2 - lz;
        }
    }
}

extern "C" void kernel_launch(void* const* d_in, const int* in_sizes, int n_in,
                              void* d_out, int out_size, void* d_ws, size_t ws_size,
                              hipStream_t stream) {
    const float* x   = (const float*)d_in[0];
    const int*   ei  = (const int*)d_in[1];
    const int*   src = ei;
    const int*   dst = ei + NE;
    const float* W1l = (const float*)d_in[2];
    const float* W1r = (const float*)d_in[3];
    const float* b1  = (const float*)d_in[4];
    const float* W2l = (const float*)d_in[5];
    const float* W2r = (const float*)d_in[6];
    const float* b2  = (const float*)d_in[7];
    float* out = (float*)d_out;

    int* ip    = (int*)d_ws;
    int* deg   = ip;              // NN
    int* loc   = ip + 100000;     // NN
    int* ofs   = ip + 200000;     // NN+1 (pad to 100004)
    int* cur   = ip + 300004;     // NN
    int* srcs  = ip + 400004;     // NE
    int* part  = ip + 1040004;    // 512
    int* part2 = ip + 1040516;    // 512
    unsigned short* up   = (unsigned short*)(ip + 1041028);  // 16B aligned
    unsigned short* xb   = up;                   // NN*DF
    unsigned short* aggb = up + 12800000;        // NN*DF
    unsigned short* hb   = up + 25600000;        // NN*DF
    unsigned short* w1p  = up + 38400000;        // 32768
    unsigned short* w2p  = up + 38432768;        // 12288

    convert_x_kernel<<<6250, 256, 0, stream>>>(x, xb);
    pack_w1_kernel<<<16, 256, 0, stream>>>(W1l, W1r, w1p);
    pack_w2_kernel<<<6, 256, 0, stream>>>(W2l, W2r, w2p);

    zero_deg_kernel<<<391, 256, 0, stream>>>(deg);
    hist_kernel<<<(NE + 255) / 256, 256, 0, stream>>>(dst, deg);
    scan_block_kernel<<<391, 256, 0, stream>>>(deg, loc, part);
    scan_part_kernel<<<1, 512, 0, stream>>>(part, part2, 391);
    add_off_kernel<<<391, 256, 0, stream>>>(loc, part2, ofs, cur);
    fill_kernel<<<(NE + 255) / 256, 256, 0, stream>>>(src, dst, cur, srcs);

    gather_mean_kernel<<<25000, 256, 0, stream>>>(xb, ofs, srcs, aggb);
    gemm1_kernel<<<1563, 256, 0, stream>>>(aggb, xb, w1p, b1, hb);
    gather_mean_kernel<<<25000, 256, 0, stream>>>(hb, ofs, srcs, aggb);
    gemm2_kernel<<<1563, 256, 0, stream>>>(aggb, hb, w2p, b2, out);
}

// Round 8
// 215.198 us; speedup vs baseline: 12.7861x; 1.1037x over previous
//
#include <hip/hip_runtime.h>
#include <math.h>

#define NN 100000   // nodes
#define NE 640000   // edges
#define DF 128      // in/hidden feat
#define DOUT 40     // out feat

typedef short bf16x8 __attribute__((ext_vector_type(8)));
typedef float f32x4 __attribute__((ext_vector_type(4)));

__device__ __forceinline__ unsigned short f2bf(float f) {
    unsigned int u = __float_as_uint(f);
    u += 0x7fffu + ((u >> 16) & 1u);   // round-to-nearest-even
    return (unsigned short)(u >> 16);
}

// ---------------- fused prep: convert x, pack W1/W2, zero deg --------------
// grid ranges: [0,6250) convert_x | [6250,6266) pack_w1 | [6266,6272) pack_w2
//              | [6272,6663) zero deg
#define PREP_CONV 6250
#define PREP_W1   (PREP_CONV + 16)
#define PREP_W2   (PREP_W1 + 6)
#define PREP_GRID (PREP_W2 + 391)

__global__ __launch_bounds__(256) void prep_kernel(const float* __restrict__ x,
                                                   unsigned short* __restrict__ xb,
                                                   const float* __restrict__ W1l,
                                                   const float* __restrict__ W1r,
                                                   unsigned short* __restrict__ w1p,
                                                   const float* __restrict__ W2l,
                                                   const float* __restrict__ W2r,
                                                   unsigned short* __restrict__ w2p,
                                                   int* __restrict__ deg) {
    const int bid = blockIdx.x;
    const int tid = threadIdx.x;
    if (bid < PREP_CONV) {
        int i = (bid * 256 + tid) * 8;
        float4 a = *reinterpret_cast<const float4*>(x + i);
        float4 b = *reinterpret_cast<const float4*>(x + i + 4);
        uint4 o;
        o.x = (unsigned)f2bf(a.x) | ((unsigned)f2bf(a.y) << 16);
        o.y = (unsigned)f2bf(a.z) | ((unsigned)f2bf(a.w) << 16);
        o.z = (unsigned)f2bf(b.x) | ((unsigned)f2bf(b.y) << 16);
        o.w = (unsigned)f2bf(b.z) | ((unsigned)f2bf(b.w) << 16);
        *reinterpret_cast<uint4*>(xb + (size_t)i) = o;
    } else if (bid < PREP_W1) {
        // B-frag: lane holds B[k=(lane>>4)*8+j][col=ct*16+(lane&15)]
        int t = (bid - PREP_CONV) * 256 + tid;   // 4096 = 8kt * 8ct * 64
        int lane = t & 63;
        int ct = (t >> 6) & 7;
        int kt = t >> 9;
        int c  = ct * 16 + (lane & 15);
        int k0 = (kt & 3) * 32 + (lane >> 4) * 8;
        const float* W = (kt < 4) ? W1l : W1r;
        unsigned int o[4];
#pragma unroll
        for (int j = 0; j < 4; ++j) {
            unsigned int lo = f2bf(W[(size_t)(k0 + 2 * j) * DF + c]);
            unsigned int hi = f2bf(W[(size_t)(k0 + 2 * j + 1) * DF + c]);
            o[j] = lo | (hi << 16);
        }
        uint4 v; v.x = o[0]; v.y = o[1]; v.z = o[2]; v.w = o[3];
        *reinterpret_cast<uint4*>(w1p + (size_t)t * 8) = v;
    } else if (bid < PREP_W2) {
        int t = (bid - PREP_W1) * 256 + tid;     // 1536 = 8kt * 3ct * 64
        if (t < 1536) {
            int lane = t & 63;
            int g  = t >> 6;
            int ct = g % 3;
            int kt = g / 3;
            int c  = ct * 16 + (lane & 15);
            int k0 = (kt & 3) * 32 + (lane >> 4) * 8;
            const float* W = (kt < 4) ? W2l : W2r;
            unsigned int o[4];
#pragma unroll
            for (int j = 0; j < 4; ++j) {
                unsigned int lo = (c < DOUT) ? f2bf(W[(size_t)(k0 + 2 * j) * DOUT + c]) : 0u;
                unsigned int hi = (c < DOUT) ? f2bf(W[(size_t)(k0 + 2 * j + 1) * DOUT + c]) : 0u;
                o[j] = lo | (hi << 16);
            }
            uint4 v; v.x = o[0]; v.y = o[1]; v.z = o[2]; v.w = o[3];
            *reinterpret_cast<uint4*>(w2p + (size_t)t * 8) = v;
        }
    } else {
        int i = (bid - PREP_W2) * 256 + tid;
        if (i < NN) deg[i] = 0;
    }
}

// ---------------- CSR build ----------------

__global__ __launch_bounds__(256) void hist_kernel(const int* __restrict__ dst,
                                                   int* __restrict__ deg) {
    int e = blockIdx.x * blockDim.x + threadIdx.x;
    if (e < NE) atomicAdd(&deg[dst[e]], 1);
}

// per-block exclusive scan of deg -> loc(local), block sums -> part
__global__ __launch_bounds__(256) void scan_block_kernel(const int* __restrict__ deg,
                                                         int* __restrict__ loc,
                                                         int* __restrict__ part) {
    __shared__ int tmp[256];
    const int t = threadIdx.x;
    const int i = blockIdx.x * 256 + t;
    int v = (i < NN) ? deg[i] : 0;
    tmp[t] = v;
    __syncthreads();
    for (int off = 1; off < 256; off <<= 1) {
        int a = (t >= off) ? tmp[t - off] : 0;
        __syncthreads();
        tmp[t] += a;
        __syncthreads();
    }
    if (i < NN) loc[i] = tmp[t] - v;
    if (t == 255) part[blockIdx.x] = tmp[t];
}

// fused: block computes its own prefix over part[], then finalizes ofs/cur
__global__ __launch_bounds__(256) void add_off_kernel(const int* __restrict__ loc,
                                                      const int* __restrict__ part,
                                                      int* __restrict__ ofs,
                                                      int* __restrict__ cur) {
    __shared__ int wsum[4];
    const int bb = blockIdx.x;
    const int t  = threadIdx.x;
    int psum = 0;
    for (int i = t; i < bb; i += 256) psum += part[i];
#pragma unroll
    for (int off = 32; off > 0; off >>= 1) psum += __shfl_down(psum, off);
    if ((t & 63) == 0) wsum[t >> 6] = psum;
    __syncthreads();
    int base = wsum[0] + wsum[1] + wsum[2] + wsum[3];
    int i = bb * 256 + t;
    if (i < NN) {
        int o = loc[i] + base;
        ofs[i] = o;
        cur[i] = o;
    }
    if (i == 0) ofs[NN] = NE;
}

__global__ __launch_bounds__(256) void fill_kernel(const int* __restrict__ src,
                                                   const int* __restrict__ dst,
                                                   int* __restrict__ cur,
                                                   int* __restrict__ srcs) {
    int e = blockIdx.x * blockDim.x + threadIdx.x;
    if (e < NE) {
        int pos = atomicAdd(&cur[dst[e]], 1);
        srcs[pos] = src[e];
    }
}

// ---------------- gather-mean (bf16 in -> bf16 out) ----------------
// one wave per node; lane holds 2 bf16 of the 128-dim row.
// unroll-8 fully-predicated batches: all guards are wave-uniform (scalar
// branches), so up to 8 independent row-gathers are in flight per step.
__global__ __launch_bounds__(256) void gather_mean_kernel(const unsigned short* __restrict__ feat,
                                                          const int* __restrict__ ofs,
                                                          const int* __restrict__ srcs,
                                                          unsigned short* __restrict__ agg) {
    const int gid  = blockIdx.x * 256 + threadIdx.x;
    const int node = gid >> 6;
    const int lane = threadIdx.x & 63;
    if (node >= NN) return;
    const int b = ofs[node];
    const int e = ofs[node + 1];
    const unsigned short* fp = feat + lane * 2;

    float ax0 = 0.f, ay0 = 0.f, ax1 = 0.f, ay1 = 0.f;
    float ax2 = 0.f, ay2 = 0.f, ax3 = 0.f, ay3 = 0.f;

    for (int j = b; j < e; j += 8) {
        int s[8];
#pragma unroll
        for (int k = 0; k < 8; ++k)
            s[k] = (j + k < e) ? srcs[j + k] : -1;
        unsigned int v[8];
#pragma unroll
        for (int k = 0; k < 8; ++k)
            v[k] = ((unsigned)s[k] < (unsigned)NN)
                 ? *reinterpret_cast<const unsigned int*>(fp + (size_t)s[k] * DF) : 0u;
        ax0 += __uint_as_float(v[0] << 16);  ay0 += __uint_as_float(v[0] & 0xffff0000u);
        ax1 += __uint_as_float(v[1] << 16);  ay1 += __uint_as_float(v[1] & 0xffff0000u);
        ax2 += __uint_as_float(v[2] << 16);  ay2 += __uint_as_float(v[2] & 0xffff0000u);
        ax3 += __uint_as_float(v[3] << 16);  ay3 += __uint_as_float(v[3] & 0xffff0000u);
        ax0 += __uint_as_float(v[4] << 16);  ay0 += __uint_as_float(v[4] & 0xffff0000u);
        ax1 += __uint_as_float(v[5] << 16);  ay1 += __uint_as_float(v[5] & 0xffff0000u);
        ax2 += __uint_as_float(v[6] << 16);  ay2 += __uint_as_float(v[6] & 0xffff0000u);
        ax3 += __uint_as_float(v[7] << 16);  ay3 += __uint_as_float(v[7] & 0xffff0000u);
    }

    float ax = (ax0 + ax1) + (ax2 + ax3);
    float ay = (ay0 + ay1) + (ay2 + ay3);
    const float sc = 1.0f / fmaxf((float)(e - b), 1.0f);
    unsigned int o = (unsigned)f2bf(ax * sc) | ((unsigned)f2bf(ay * sc) << 16);
    *reinterpret_cast<unsigned int*>(agg + (size_t)node * DF + lane * 2) = o;
}

// ---------------- MFMA GEMMs ----------------
// A-frag: lane holds A[row = lane&15][k = (lane>>4)*8 + j]
#define G_ROWS 64
#define LDSW 136

__global__ __launch_bounds__(256) void gemm1_kernel(const unsigned short* __restrict__ aggb,
                                                    const unsigned short* __restrict__ xb,
                                                    const unsigned short* __restrict__ w1p,
                                                    const float* __restrict__ b1,
                                                    unsigned short* __restrict__ hb) {
    __shared__ unsigned short sA[G_ROWS * LDSW];
    __shared__ unsigned short sX[G_ROWS * LDSW];
    const int t = threadIdx.x;
    const int row0 = blockIdx.x * G_ROWS;

    for (int i = t; i < G_ROWS * 16; i += 256) {
        int r = i >> 4, ch = i & 15;
        int sr = row0 + r; if (sr > NN - 1) sr = NN - 1;
        *reinterpret_cast<uint4*>(&sA[r * LDSW + ch * 8]) =
            *reinterpret_cast<const uint4*>(aggb + (size_t)sr * DF + ch * 8);
        *reinterpret_cast<uint4*>(&sX[r * LDSW + ch * 8]) =
            *reinterpret_cast<const uint4*>(xb + (size_t)sr * DF + ch * 8);
    }
    __syncthreads();

    const int lane = t & 63;
    const int w = t >> 6;
    const int lr = lane & 15;
    const int hi = lane >> 4;
    f32x4 acc[8];
#pragma unroll
    for (int i = 0; i < 8; ++i) acc[i] = (f32x4){0.f, 0.f, 0.f, 0.f};

    const int arow = (w * 16 + lr) * LDSW + hi * 8;
#pragma unroll
    for (int half = 0; half < 2; ++half) {
        const unsigned short* base = half ? sX : sA;
#pragma unroll
        for (int kq = 0; kq < 4; ++kq) {
            bf16x8 a = __builtin_bit_cast(bf16x8,
                *reinterpret_cast<const uint4*>(&base[arow + kq * 32]));
            const unsigned short* wp = w1p + (size_t)(((half * 4 + kq) * 8) * 64 + lane) * 8;
#pragma unroll
            for (int ct = 0; ct < 8; ++ct) {
                bf16x8 b = __builtin_bit_cast(bf16x8,
                    *reinterpret_cast<const uint4*>(wp + ct * 512));
                acc[ct] = __builtin_amdgcn_mfma_f32_16x16x32_bf16(a, b, acc[ct], 0, 0, 0);
            }
        }
    }

#pragma unroll
    for (int ct = 0; ct < 8; ++ct) {
        int col = ct * 16 + lr;
        float bias = b1[col];
#pragma unroll
        for (int v = 0; v < 4; ++v) {
            int row = row0 + w * 16 + hi * 4 + v;
            if (row < NN) {
                float o = fmaxf(acc[ct][v] + bias, 0.f);
                hb[(size_t)row * DF + col] = f2bf(o);
            }
        }
    }
}

__global__ __launch_bounds__(256) void gemm2_kernel(const unsigned short* __restrict__ aggb,
                                                    const unsigned short* __restrict__ hb,
                                                    const unsigned short* __restrict__ w2p,
                                                    const float* __restrict__ b2,
                                                    float* __restrict__ out) {
    __shared__ unsigned short sA[G_ROWS * LDSW];
    __shared__ unsigned short sH[G_ROWS * LDSW];
    const int t = threadIdx.x;
    const int row0 = blockIdx.x * G_ROWS;

    for (int i = t; i < G_ROWS * 16; i += 256) {
        int r = i >> 4, ch = i & 15;
        int sr = row0 + r; if (sr > NN - 1) sr = NN - 1;
        *reinterpret_cast<uint4*>(&sA[r * LDSW + ch * 8]) =
            *reinterpret_cast<const uint4*>(aggb + (size_t)sr * DF + ch * 8);
        *reinterpret_cast<uint4*>(&sH[r * LDSW + ch * 8]) =
            *reinterpret_cast<const uint4*>(hb + (size_t)sr * DF + ch * 8);
    }
    __syncthreads();

    const int lane = t & 63;
    const int w = t >> 6;
    const int lr = lane & 15;
    const int hi = lane >> 4;
    f32x4 acc[3];
#pragma unroll
    for (int i = 0; i < 3; ++i) acc[i] = (f32x4){0.f, 0.f, 0.f, 0.f};

    const int arow = (w * 16 + lr) * LDSW + hi * 8;
#pragma unroll
    for (int half = 0; half < 2; ++half) {
        const unsigned short* base = half ? sH : sA;
#pragma unroll
        for (int kq = 0; kq < 4; ++kq) {
            bf16x8 a = __builtin_bit_cast(bf16x8,
                *reinterpret_cast<const uint4*>(&base[arow + kq * 32]));
            const unsigned short* wp = w2p + (size_t)(((half * 4 + kq) * 3) * 64 + lane) * 8;
#pragma unroll
            for (int ct = 0; ct < 3; ++ct) {
                bf16x8 b = __builtin_bit_cast(bf16x8,
                    *reinterpret_cast<const uint4*>(wp + ct * 512));
                acc[ct] = __builtin_amdgcn_mfma_f32_16x16x32_bf16(a, b, acc[ct], 0, 0, 0);
            }
        }
    }

    // bias + log_softmax over 40 cols, per C-fragment row
    const int c = lr;
    float bb0 = b2[c];
    float bb1 = b2[16 + c];
    float bb2 = (c < 8) ? b2[32 + c] : 0.f;

#pragma unroll
    for (int v = 0; v < 4; ++v) {
        float l0 = acc[0][v] + bb0;
        float l1 = acc[1][v] + bb1;
        float l2 = (c < 8) ? (acc[2][v] + bb2) : -INFINITY;
        float mx = fmaxf(fmaxf(l0, l1), l2);
        mx = fmaxf(mx, __shfl_xor(mx, 1));
        mx = fmaxf(mx, __shfl_xor(mx, 2));
        mx = fmaxf(mx, __shfl_xor(mx, 4));
        mx = fmaxf(mx, __shfl_xor(mx, 8));
        float s = __expf(l0 - mx) + __expf(l1 - mx) + ((c < 8) ? __expf(l2 - mx) : 0.f);
        s += __shfl_xor(s, 1);
        s += __shfl_xor(s, 2);
        s += __shfl_xor(s, 4);
        s += __shfl_xor(s, 8);
        float lz = mx + __logf(s);
        int row = row0 + w * 16 + hi * 4 + v;
        if (row < NN) {
            out[(size_t)row * DOUT + c]      = l0 - lz;
            out[(size_t)row * DOUT + 16 + c] = l1 - lz;
            if (c < 8) out[(size_t)row * DOUT + 32 + c] = l2 - lz;
        }
    }
}

extern "C" void kernel_launch(void* const* d_in, const int* in_sizes, int n_in,
                              void* d_out, int out_size, void* d_ws, size_t ws_size,
                              hipStream_t stream) {
    const float* x   = (const float*)d_in[0];
    const int*   ei  = (const int*)d_in[1];
    const int*   src = ei;
    const int*   dst = ei + NE;
    const float* W1l = (const float*)d_in[2];
    const float* W1r = (const float*)d_in[3];
    const float* b1  = (const float*)d_in[4];
    const float* W2l = (const float*)d_in[5];
    const float* W2r = (const float*)d_in[6];
    const float* b2  = (const float*)d_in[7];
    float* out = (float*)d_out;

    int* ip    = (int*)d_ws;
    int* deg   = ip;              // NN
    int* loc   = ip + 100000;     // NN
    int* ofs   = ip + 200000;     // NN+1 (pad to 100004)
    int* cur   = ip + 300004;     // NN
    int* srcs  = ip + 400004;     // NE (+8 pad)
    int* part  = ip + 1040012;    // 512
    unsigned short* up   = (unsigned short*)(ip + 1040524);  // 16B aligned (even)
    unsigned short* xb   = up;                   // NN*DF
    unsigned short* aggb = up + 12800000;        // NN*DF
    unsigned short* hb   = up + 25600000;        // NN*DF
    unsigned short* w1p  = up + 38400000;        // 32768
    unsigned short* w2p  = up + 38432768;        // 12288

    prep_kernel<<<PREP_GRID, 256, 0, stream>>>(x, xb, W1l, W1r, w1p, W2l, W2r, w2p, deg);

    hist_kernel<<<(NE + 255) / 256, 256, 0, stream>>>(dst, deg);
    scan_block_kernel<<<391, 256, 0, stream>>>(deg, loc, part);
    add_off_kernel<<<391, 256, 0, stream>>>(loc, part, ofs, cur);
    fill_kernel<<<(NE + 255) / 256, 256, 0, stream>>>(src, dst, cur, srcs);

    gather_mean_kernel<<<25000, 256, 0, stream>>>(xb, ofs, srcs, aggb);
    gemm1_kernel<<<1563, 256, 0, stream>>>(aggb, xb, w1p, b1, hb);
    gather_mean_kernel<<<25000, 256, 0, stream>>>(hb, ofs, srcs, aggb);
    gemm2_kernel<<<1563, 256, 0, stream>>>(aggb, hb, w2p, b2, out);
}

// Round 9
// 182.975 us; speedup vs baseline: 15.0378x; 1.1761x over previous
//
#include <hip/hip_runtime.h>
#include <math.h>

#define NN 100000   // nodes
#define NE 640000   // edges
#define DF 128      // in/hidden feat
#define DOUT 40     // out feat

typedef short bf16x8 __attribute__((ext_vector_type(8)));
typedef float f32x4 __attribute__((ext_vector_type(4)));

__device__ __forceinline__ unsigned short f2bf(float f) {
    unsigned int u = __float_as_uint(f);
    u += 0x7fffu + ((u >> 16) & 1u);   // round-to-nearest-even
    return (unsigned short)(u >> 16);
}
__device__ __forceinline__ float bf2f(unsigned short u) {
    return __uint_as_float((unsigned int)u << 16);
}

// ---------------- fused prep: convert x, pack W1/W2, zero deg --------------
#define PREP_CONV 6250
#define PREP_W1   (PREP_CONV + 16)
#define PREP_W2   (PREP_W1 + 6)
#define PREP_GRID (PREP_W2 + 391)

__global__ __launch_bounds__(256) void prep_kernel(const float* __restrict__ x,
                                                   unsigned short* __restrict__ xb,
                                                   const float* __restrict__ W1l,
                                                   const float* __restrict__ W1r,
                                                   unsigned short* __restrict__ w1p,
                                                   const float* __restrict__ W2l,
                                                   const float* __restrict__ W2r,
                                                   unsigned short* __restrict__ w2lp,
                                                   unsigned short* __restrict__ w2rp,
                                                   int* __restrict__ deg) {
    const int bid = blockIdx.x;
    const int tid = threadIdx.x;
    if (bid < PREP_CONV) {
        int i = (bid * 256 + tid) * 8;
        float4 a = *reinterpret_cast<const float4*>(x + i);
        float4 b = *reinterpret_cast<const float4*>(x + i + 4);
        uint4 o;
        o.x = (unsigned)f2bf(a.x) | ((unsigned)f2bf(a.y) << 16);
        o.y = (unsigned)f2bf(a.z) | ((unsigned)f2bf(a.w) << 16);
        o.z = (unsigned)f2bf(b.x) | ((unsigned)f2bf(b.y) << 16);
        o.w = (unsigned)f2bf(b.z) | ((unsigned)f2bf(b.w) << 16);
        *reinterpret_cast<uint4*>(xb + (size_t)i) = o;
    } else if (bid < PREP_W1) {
        // B-frag: lane holds B[k=(lane>>4)*8+j][col=ct*16+(lane&15)]
        int t = (bid - PREP_CONV) * 256 + tid;   // 4096 = 8kt * 8ct * 64
        int lane = t & 63;
        int ct = (t >> 6) & 7;
        int kt = t >> 9;
        int c  = ct * 16 + (lane & 15);
        int k0 = (kt & 3) * 32 + (lane >> 4) * 8;
        const float* W = (kt < 4) ? W1l : W1r;
        unsigned int o[4];
#pragma unroll
        for (int j = 0; j < 4; ++j) {
            unsigned int lo = f2bf(W[(size_t)(k0 + 2 * j) * DF + c]);
            unsigned int hi = f2bf(W[(size_t)(k0 + 2 * j + 1) * DF + c]);
            o[j] = lo | (hi << 16);
        }
        uint4 v; v.x = o[0]; v.y = o[1]; v.z = o[2]; v.w = o[3];
        *reinterpret_cast<uint4*>(w1p + (size_t)t * 8) = v;
    } else if (bid < PREP_W2) {
        int t = (bid - PREP_W1) * 256 + tid;     // 1536 = 2 * 4kt * 3ct * 64
        if (t < 1536) {
            int lane = t & 63;
            int g  = t >> 6;       // 0..23
            int ct = g % 3;
            int kt = g / 3;        // 0..7; <4 -> W2l, else W2r
            int c  = ct * 16 + (lane & 15);
            int k0 = (kt & 3) * 32 + (lane >> 4) * 8;
            const float* W = (kt < 4) ? W2l : W2r;
            unsigned short* dstp = (kt < 4) ? w2lp : w2rp;
            int slot = ((kt & 3) * 3 + ct) * 64 + lane;
            unsigned int o[4];
#pragma unroll
            for (int j = 0; j < 4; ++j) {
                unsigned int lo = (c < DOUT) ? f2bf(W[(size_t)(k0 + 2 * j) * DOUT + c]) : 0u;
                unsigned int hi = (c < DOUT) ? f2bf(W[(size_t)(k0 + 2 * j + 1) * DOUT + c]) : 0u;
                o[j] = lo | (hi << 16);
            }
            uint4 v; v.x = o[0]; v.y = o[1]; v.z = o[2]; v.w = o[3];
            *reinterpret_cast<uint4*>(dstp + (size_t)slot * 8) = v;
        }
    } else {
        int i = (bid - PREP_W2) * 256 + tid;
        if (i < NN) deg[i] = 0;
    }
}

// ---------------- CSR build ----------------

// hist + per-edge rank (old count) so fill needs no atomics
__global__ __launch_bounds__(256) void hist_kernel(const int* __restrict__ dst,
                                                   int* __restrict__ deg,
                                                   int* __restrict__ rank) {
    int e = blockIdx.x * blockDim.x + threadIdx.x;
    if (e < NE) rank[e] = atomicAdd(&deg[dst[e]], 1);
}

// per-block exclusive scan of deg -> loc(local), block sums -> part
__global__ __launch_bounds__(256) void scan_block_kernel(const int* __restrict__ deg,
                                                         int* __restrict__ loc,
                                                         int* __restrict__ part) {
    __shared__ int tmp[256];
    const int t = threadIdx.x;
    const int i = blockIdx.x * 256 + t;
    int v = (i < NN) ? deg[i] : 0;
    tmp[t] = v;
    __syncthreads();
    for (int off = 1; off < 256; off <<= 1) {
        int a = (t >= off) ? tmp[t - off] : 0;
        __syncthreads();
        tmp[t] += a;
        __syncthreads();
    }
    if (i < NN) loc[i] = tmp[t] - v;
    if (t == 255) part[blockIdx.x] = tmp[t];
}

// fused: block computes its own prefix over part[], then finalizes ofs
__global__ __launch_bounds__(256) void add_off_kernel(const int* __restrict__ loc,
                                                      const int* __restrict__ part,
                                                      int* __restrict__ ofs) {
    __shared__ int wsum[4];
    const int bb = blockIdx.x;
    const int t  = threadIdx.x;
    int psum = 0;
    for (int i = t; i < bb; i += 256) psum += part[i];
#pragma unroll
    for (int off = 32; off > 0; off >>= 1) psum += __shfl_down(psum, off);
    if ((t & 63) == 0) wsum[t >> 6] = psum;
    __syncthreads();
    int base = wsum[0] + wsum[1] + wsum[2] + wsum[3];
    int i = bb * 256 + t;
    if (i < NN) ofs[i] = loc[i] + base;
    if (i == 0) ofs[NN] = NE;
}

// atomic-free bucket fill: pos = ofs[dst] + rank
__global__ __launch_bounds__(256) void fill_kernel(const int* __restrict__ src,
                                                   const int* __restrict__ dst,
                                                   const int* __restrict__ ofs,
                                                   const int* __restrict__ rank,
                                                   int* __restrict__ srcs) {
    int e = blockIdx.x * blockDim.x + threadIdx.x;
    if (e < NE) {
        int d = dst[e];
        srcs[ofs[d] + rank[e]] = src[e];
    }
}

// ---------------- gather-mean, 128-dim (bf16 in -> bf16 out) ---------------
// one wave per node; lane holds 2 bf16 of the 128-dim row; unroll-8 batches.
__global__ __launch_bounds__(256) void gather_mean_kernel(const unsigned short* __restrict__ feat,
                                                          const int* __restrict__ ofs,
                                                          const int* __restrict__ srcs,
                                                          unsigned short* __restrict__ agg) {
    const int gid  = blockIdx.x * 256 + threadIdx.x;
    const int node = gid >> 6;
    const int lane = threadIdx.x & 63;
    if (node >= NN) return;
    const int b = ofs[node];
    const int e = ofs[node + 1];
    const unsigned short* fp = feat + lane * 2;

    float ax0 = 0.f, ay0 = 0.f, ax1 = 0.f, ay1 = 0.f;
    float ax2 = 0.f, ay2 = 0.f, ax3 = 0.f, ay3 = 0.f;

    for (int j = b; j < e; j += 8) {
        int s[8];
#pragma unroll
        for (int k = 0; k < 8; ++k)
            s[k] = (j + k < e) ? srcs[j + k] : -1;
        unsigned int v[8];
#pragma unroll
        for (int k = 0; k < 8; ++k)
            v[k] = ((unsigned)s[k] < (unsigned)NN)
                 ? *reinterpret_cast<const unsigned int*>(fp + (size_t)s[k] * DF) : 0u;
        ax0 += __uint_as_float(v[0] << 16);  ay0 += __uint_as_float(v[0] & 0xffff0000u);
        ax1 += __uint_as_float(v[1] << 16);  ay1 += __uint_as_float(v[1] & 0xffff0000u);
        ax2 += __uint_as_float(v[2] << 16);  ay2 += __uint_as_float(v[2] & 0xffff0000u);
        ax3 += __uint_as_float(v[3] << 16);  ay3 += __uint_as_float(v[3] & 0xffff0000u);
        ax0 += __uint_as_float(v[4] << 16);  ay0 += __uint_as_float(v[4] & 0xffff0000u);
        ax1 += __uint_as_float(v[5] << 16);  ay1 += __uint_as_float(v[5] & 0xffff0000u);
        ax2 += __uint_as_float(v[6] << 16);  ay2 += __uint_as_float(v[6] & 0xffff0000u);
        ax3 += __uint_as_float(v[7] << 16);  ay3 += __uint_as_float(v[7] & 0xffff0000u);
    }

    float ax = (ax0 + ax1) + (ax2 + ax3);
    float ay = (ay0 + ay1) + (ay2 + ay3);
    const float sc = 1.0f / fmaxf((float)(e - b), 1.0f);
    unsigned int o = (unsigned)f2bf(ax * sc) | ((unsigned)f2bf(ay * sc) << 16);
    *reinterpret_cast<unsigned int*>(agg + (size_t)node * DF + lane * 2) = o;
}

// ---------------- gather-mean, 48-dim (h2 rows) ----------------------------
// one wave per node; lanes 0..23 hold 2 bf16 of the 48-dim row.
#define D2 48
__global__ __launch_bounds__(256) void gather_mean48_kernel(const unsigned short* __restrict__ feat,
                                                            const int* __restrict__ ofs,
                                                            const int* __restrict__ srcs,
                                                            unsigned short* __restrict__ agg) {
    const int gid  = blockIdx.x * 256 + threadIdx.x;
    const int node = gid >> 6;
    const int lane = threadIdx.x & 63;
    if (node >= NN) return;
    const int b = ofs[node];
    const int e = ofs[node + 1];
    const bool act = lane < 24;
    const unsigned short* fp = feat + lane * 2;

    float ax0 = 0.f, ay0 = 0.f, ax1 = 0.f, ay1 = 0.f;
    float ax2 = 0.f, ay2 = 0.f, ax3 = 0.f, ay3 = 0.f;

    for (int j = b; j < e; j += 8) {
        int s[8];
#pragma unroll
        for (int k = 0; k < 8; ++k)
            s[k] = (j + k < e) ? srcs[j + k] : -1;
        unsigned int v[8];
#pragma unroll
        for (int k = 0; k < 8; ++k)
            v[k] = (act && (unsigned)s[k] < (unsigned)NN)
                 ? *reinterpret_cast<const unsigned int*>(fp + (size_t)s[k] * D2) : 0u;
        ax0 += __uint_as_float(v[0] << 16);  ay0 += __uint_as_float(v[0] & 0xffff0000u);
        ax1 += __uint_as_float(v[1] << 16);  ay1 += __uint_as_float(v[1] & 0xffff0000u);
        ax2 += __uint_as_float(v[2] << 16);  ay2 += __uint_as_float(v[2] & 0xffff0000u);
        ax3 += __uint_as_float(v[3] << 16);  ay3 += __uint_as_float(v[3] & 0xffff0000u);
        ax0 += __uint_as_float(v[4] << 16);  ay0 += __uint_as_float(v[4] & 0xffff0000u);
        ax1 += __uint_as_float(v[5] << 16);  ay1 += __uint_as_float(v[5] & 0xffff0000u);
        ax2 += __uint_as_float(v[6] << 16);  ay2 += __uint_as_float(v[6] & 0xffff0000u);
        ax3 += __uint_as_float(v[7] << 16);  ay3 += __uint_as_float(v[7] & 0xffff0000u);
    }

    float ax = (ax0 + ax1) + (ax2 + ax3);
    float ay = (ay0 + ay1) + (ay2 + ay3);
    const float sc = 1.0f / fmaxf((float)(e - b), 1.0f);
    if (act) {
        unsigned int o = (unsigned)f2bf(ax * sc) | ((unsigned)f2bf(ay * sc) << 16);
        *reinterpret_cast<unsigned int*>(agg + (size_t)node * D2 + lane * 2) = o;
    }
}

// ---------------- MFMA GEMMs ----------------
// A-frag: lane holds A[row = lane&15][k = (lane>>4)*8 + j]
#define G_ROWS 64
#define LDSW 136

// stage 1: h = relu(agg@W1l + x@W1r + b1); stage 2: h2 = h @ W2l  [NN,48]
__global__ __launch_bounds__(256) void gemm1_kernel(const unsigned short* __restrict__ aggb,
                                                    const unsigned short* __restrict__ xb,
                                                    const unsigned short* __restrict__ w1p,
                                                    const unsigned short* __restrict__ w2lp,
                                                    const float* __restrict__ b1,
                                                    unsigned short* __restrict__ hb,
                                                    unsigned short* __restrict__ h2b) {
    __shared__ unsigned short sA[G_ROWS * LDSW];
    __shared__ unsigned short sX[G_ROWS * LDSW];
    const int t = threadIdx.x;
    const int row0 = blockIdx.x * G_ROWS;

    for (int i = t; i < G_ROWS * 16; i += 256) {
        int r = i >> 4, ch = i & 15;
        int sr = row0 + r; if (sr > NN - 1) sr = NN - 1;
        *reinterpret_cast<uint4*>(&sA[r * LDSW + ch * 8]) =
            *reinterpret_cast<const uint4*>(aggb + (size_t)sr * DF + ch * 8);
        *reinterpret_cast<uint4*>(&sX[r * LDSW + ch * 8]) =
            *reinterpret_cast<const uint4*>(xb + (size_t)sr * DF + ch * 8);
    }
    __syncthreads();

    const int lane = t & 63;
    const int w = t >> 6;
    const int lr = lane & 15;
    const int hi = lane >> 4;
    f32x4 acc[8];
#pragma unroll
    for (int i = 0; i < 8; ++i) acc[i] = (f32x4){0.f, 0.f, 0.f, 0.f};

    const int arow = (w * 16 + lr) * LDSW + hi * 8;
#pragma unroll
    for (int half = 0; half < 2; ++half) {
        const unsigned short* base = half ? sX : sA;
#pragma unroll
        for (int kq = 0; kq < 4; ++kq) {
            bf16x8 a = __builtin_bit_cast(bf16x8,
                *reinterpret_cast<const uint4*>(&base[arow + kq * 32]));
            const unsigned short* wp = w1p + (size_t)(((half * 4 + kq) * 8) * 64 + lane) * 8;
#pragma unroll
            for (int ct = 0; ct < 8; ++ct) {
                bf16x8 b = __builtin_bit_cast(bf16x8,
                    *reinterpret_cast<const uint4*>(wp + ct * 512));
                acc[ct] = __builtin_amdgcn_mfma_f32_16x16x32_bf16(a, b, acc[ct], 0, 0, 0);
            }
        }
    }

    // relu + bias -> bf16; store h to global, stash for LDS round-trip
    unsigned short hreg[8][4];
#pragma unroll
    for (int ct = 0; ct < 8; ++ct) {
        int col = ct * 16 + lr;
        float bias = b1[col];
#pragma unroll
        for (int v = 0; v < 4; ++v) {
            float o = fmaxf(acc[ct][v] + bias, 0.f);
            hreg[ct][v] = f2bf(o);
            int row = row0 + w * 16 + hi * 4 + v;
            if (row < NN) hb[(size_t)row * DF + col] = hreg[ct][v];
        }
    }

    __syncthreads();   // all stage-1 LDS reads done before overwrite
    // write h tile into sA (row-major, LDSW stride)
#pragma unroll
    for (int ct = 0; ct < 8; ++ct) {
#pragma unroll
        for (int v = 0; v < 4; ++v) {
            sA[(w * 16 + hi * 4 + v) * LDSW + ct * 16 + lr] = hreg[ct][v];
        }
    }
    __syncthreads();

    // stage 2: h2 = h @ W2l (48 padded cols)
    f32x4 acc2[3];
#pragma unroll
    for (int i = 0; i < 3; ++i) acc2[i] = (f32x4){0.f, 0.f, 0.f, 0.f};
#pragma unroll
    for (int kq = 0; kq < 4; ++kq) {
        bf16x8 a = __builtin_bit_cast(bf16x8,
            *reinterpret_cast<const uint4*>(&sA[arow + kq * 32]));
        const unsigned short* wp = w2lp + (size_t)((kq * 3) * 64 + lane) * 8;
#pragma unroll
        for (int ct = 0; ct < 3; ++ct) {
            bf16x8 b = __builtin_bit_cast(bf16x8,
                *reinterpret_cast<const uint4*>(wp + ct * 512));
            acc2[ct] = __builtin_amdgcn_mfma_f32_16x16x32_bf16(a, b, acc2[ct], 0, 0, 0);
        }
    }
#pragma unroll
    for (int ct = 0; ct < 3; ++ct) {
        int col = ct * 16 + lr;
#pragma unroll
        for (int v = 0; v < 4; ++v) {
            int row = row0 + w * 16 + hi * 4 + v;
            if (row < NN) h2b[(size_t)row * D2 + col] = f2bf(acc2[ct][v]);
        }
    }
}

// out = log_softmax( agg2 + h @ W2r + b2 ),  [NN,40]
__global__ __launch_bounds__(256) void gemm2_kernel(const unsigned short* __restrict__ agg2b,
                                                    const unsigned short* __restrict__ hb,
                                                    const unsigned short* __restrict__ w2rp,
                                                    const float* __restrict__ b2,
                                                    float* __restrict__ out) {
    __shared__ unsigned short sH[G_ROWS * LDSW];
    __shared__ unsigned short sG[G_ROWS * D2];
    const int t = threadIdx.x;
    const int row0 = blockIdx.x * G_ROWS;

    for (int i = t; i < G_ROWS * 16; i += 256) {
        int r = i >> 4, ch = i & 15;
        int sr = row0 + r; if (sr > NN - 1) sr = NN - 1;
        *reinterpret_cast<uint4*>(&sH[r * LDSW + ch * 8]) =
            *reinterpret_cast<const uint4*>(hb + (size_t)sr * DF + ch * 8);
    }
    for (int i = t; i < G_ROWS * 24; i += 256) {
        int r = i / 24, c = i % 24;
        int sr = row0 + r; if (sr > NN - 1) sr = NN - 1;
        *reinterpret_cast<unsigned int*>(&sG[r * D2 + c * 2]) =
            *reinterpret_cast<const unsigned int*>(agg2b + (size_t)sr * D2 + c * 2);
    }
    __syncthreads();

    const int lane = t & 63;
    const int w = t >> 6;
    const int lr = lane & 15;
    const int hi = lane >> 4;
    f32x4 acc[3];
#pragma unroll
    for (int i = 0; i < 3; ++i) acc[i] = (f32x4){0.f, 0.f, 0.f, 0.f};

    const int arow = (w * 16 + lr) * LDSW + hi * 8;
#pragma unroll
    for (int kq = 0; kq < 4; ++kq) {
        bf16x8 a = __builtin_bit_cast(bf16x8,
            *reinterpret_cast<const uint4*>(&sH[arow + kq * 32]));
        const unsigned short* wp = w2rp + (size_t)((kq * 3) * 64 + lane) * 8;
#pragma unroll
        for (int ct = 0; ct < 3; ++ct) {
            bf16x8 b = __builtin_bit_cast(bf16x8,
                *reinterpret_cast<const uint4*>(wp + ct * 512));
            acc[ct] = __builtin_amdgcn_mfma_f32_16x16x32_bf16(a, b, acc[ct], 0, 0, 0);
        }
    }

    // add agg2 + bias, then log_softmax over 40 cols
    const int c = lr;
    float bb0 = b2[c];
    float bb1 = b2[16 + c];
    float bb2 = (c < 8) ? b2[32 + c] : 0.f;

#pragma unroll
    for (int v = 0; v < 4; ++v) {
        int lrow = w * 16 + hi * 4 + v;
        float l0 = acc[0][v] + bb0 + bf2f(sG[lrow * D2 + c]);
        float l1 = acc[1][v] + bb1 + bf2f(sG[lrow * D2 + 16 + c]);
        float l2 = (c < 8) ? (acc[2][v] + bb2 + bf2f(sG[lrow * D2 + 32 + c])) : -INFINITY;
        float mx = fmaxf(fmaxf(l0, l1), l2);
        mx = fmaxf(mx, __shfl_xor(mx, 1));
        mx = fmaxf(mx, __shfl_xor(mx, 2));
        mx = fmaxf(mx, __shfl_xor(mx, 4));
        mx = fmaxf(mx, __shfl_xor(mx, 8));
        float s = __expf(l0 - mx) + __expf(l1 - mx) + ((c < 8) ? __expf(l2 - mx) : 0.f);
        s += __shfl_xor(s, 1);
        s += __shfl_xor(s, 2);
        s += __shfl_xor(s, 4);
        s += __shfl_xor(s, 8);
        float lz = mx + __logf(s);
        int row = row0 + lrow;
        if (row < NN) {
            out[(size_t)row * DOUT + c]      = l0 - lz;
            out[(size_t)row * DOUT + 16 + c] = l1 - lz;
            if (c < 8) out[(size_t)row * DOUT + 32 + c] = l2 - lz;
        }
    }
}

extern "C" void kernel_launch(void* const* d_in, const int* in_sizes, int n_in,
                              void* d_out, int out_size, void* d_ws, size_t ws_size,
                              hipStream_t stream) {
    const float* x   = (const float*)d_in[0];
    const int*   ei  = (const int*)d_in[1];
    const int*   src = ei;
    const int*   dst = ei + NE;
    const float* W1l = (const float*)d_in[2];
    const float* W1r = (const float*)d_in[3];
    const float* b1  = (const float*)d_in[4];
    const float* W2l = (const float*)d_in[5];
    const float* W2r = (const float*)d_in[6];
    const float* b2  = (const float*)d_in[7];
    float* out = (float*)d_out;

    int* ip    = (int*)d_ws;
    int* deg   = ip;              // 100000
    int* loc   = ip + 100000;     // 100000
    int* ofs   = ip + 200000;     // 100004
    int* rank  = ip + 300004;     // 640000
    int* srcs  = ip + 940004;     // 640008
    int* part  = ip + 1580012;    // 512
    unsigned short* up    = (unsigned short*)(ip + 1580524);  // 16B aligned
    unsigned short* xb    = up;                   // NN*DF
    unsigned short* aggb  = up + 12800000;        // NN*DF
    unsigned short* hb    = up + 25600000;        // NN*DF
    unsigned short* h2b   = up + 38400000;        // NN*48
    unsigned short* agg2b = up + 43200000;        // NN*48
    unsigned short* w1p   = up + 48000000;        // 32768
    unsigned short* w2lp  = up + 48032768;        // 6144
    unsigned short* w2rp  = up + 48038912;        // 6144

    prep_kernel<<<PREP_GRID, 256, 0, stream>>>(x, xb, W1l, W1r, w1p,
                                               W2l, W2r, w2lp, w2rp, deg);

    hist_kernel<<<(NE + 255) / 256, 256, 0, stream>>>(dst, deg, rank);
    scan_block_kernel<<<391, 256, 0, stream>>>(deg, loc, part);
    add_off_kernel<<<391, 256, 0, stream>>>(loc, part, ofs);
    fill_kernel<<<(NE + 255) / 256, 256, 0, stream>>>(src, dst, ofs, rank, srcs);

    gather_mean_kernel<<<25000, 256, 0, stream>>>(xb, ofs, srcs, aggb);
    gemm1_kernel<<<1563, 256, 0, stream>>>(aggb, xb, w1p, w2lp, b1, hb, h2b);
    gather_mean48_kernel<<<25000, 256, 0, stream>>>(h2b, ofs, srcs, agg2b);
    gemm2_kernel<<<1563, 256, 0, stream>>>(agg2b, hb, w2rp, b2, out);
}

// Round 10
// 175.997 us; speedup vs baseline: 15.6340x; 1.0396x over previous
//
#include <hip/hip_runtime.h>
#include <math.h>

#define NN 100000   // nodes
#define NE 640000   // edges
#define DF 128      // in/hidden feat
#define DOUT 40     // out feat
#define D2 48       // padded W2 cols

typedef short bf16x8 __attribute__((ext_vector_type(8)));
typedef float f32x4 __attribute__((ext_vector_type(4)));
typedef float f32x2 __attribute__((ext_vector_type(2)));

#if defined(__has_builtin)
#if __has_builtin(__builtin_amdgcn_cvt_pk_f32_fp8) && __has_builtin(__builtin_amdgcn_cvt_pk_fp8_f32)
#define HW_FP8 1
#endif
#endif
#ifndef HW_FP8
#define HW_FP8 0
#endif

__device__ __forceinline__ unsigned short f2bf(float f) {
    unsigned int u = __float_as_uint(f);
    u += 0x7fffu + ((u >> 16) & 1u);   // RNE
    return (unsigned short)(u >> 16);
}
__device__ __forceinline__ float bf2f(unsigned short u) {
    return __uint_as_float((unsigned int)u << 16);
}

__device__ __forceinline__ unsigned int f2fp8_manual(float f) {
    unsigned u = __float_as_uint(f);
    unsigned s = (u >> 24) & 0x80u;
    unsigned au = u & 0x7fffffffu;
    if (au > 0x43e00000u) au = 0x43e00000u;   // clamp |x| to 448
    au += 0x7ffffu + ((au >> 20) & 1u);       // RNE to 3-bit mantissa
    if (au < 0x3c800000u) return s;           // flush < 2^-6 to 0
    unsigned e = (au >> 23) - 120u;
    return s | (e << 3) | ((au >> 20) & 7u);
}

__device__ __forceinline__ unsigned short f2fp8x2(float x, float y) {
#if HW_FP8
    int v = __builtin_amdgcn_cvt_pk_fp8_f32(x, y, 0, false);
    return (unsigned short)(v & 0xffff);
#else
    return (unsigned short)(f2fp8_manual(x) | (f2fp8_manual(y) << 8));
#endif
}

__device__ __forceinline__ void fp8pair(unsigned short p, float& x, float& y) {
#if HW_FP8
    f32x2 r = __builtin_amdgcn_cvt_pk_f32_fp8((int)(unsigned)p, false);
    x = r.x; y = r.y;
#else
    unsigned lo = p & 0xffu, hi = (p >> 8) & 0xffu;
    x = __uint_as_float(((lo & 0x80u) << 24) | ((lo & 0x7fu) << 20)) * 0x1.0p120f;
    y = __uint_as_float(((hi & 0x80u) << 24) | ((hi & 0x7fu) << 20)) * 0x1.0p120f;
#endif
}

// ---------------- fused prep: convert x (bf16 + fp8), pack W1/W2, zero deg --
#define PREP_CONV 6250
#define PREP_W1   (PREP_CONV + 16)
#define PREP_W2   (PREP_W1 + 6)
#define PREP_GRID (PREP_W2 + 391)

__global__ __launch_bounds__(256) void prep_kernel(const float* __restrict__ x,
                                                   unsigned short* __restrict__ xb,
                                                   unsigned char* __restrict__ xq,
                                                   const float* __restrict__ W1l,
                                                   const float* __restrict__ W1r,
                                                   unsigned short* __restrict__ w1p,
                                                   const float* __restrict__ W2l,
                                                   const float* __restrict__ W2r,
                                                   unsigned short* __restrict__ w2lp,
                                                   unsigned short* __restrict__ w2rp,
                                                   int* __restrict__ deg) {
    const int bid = blockIdx.x;
    const int tid = threadIdx.x;
    if (bid < PREP_CONV) {
        int i = (bid * 256 + tid) * 8;
        float4 a = *reinterpret_cast<const float4*>(x + i);
        float4 b = *reinterpret_cast<const float4*>(x + i + 4);
        uint4 o;
        o.x = (unsigned)f2bf(a.x) | ((unsigned)f2bf(a.y) << 16);
        o.y = (unsigned)f2bf(a.z) | ((unsigned)f2bf(a.w) << 16);
        o.z = (unsigned)f2bf(b.x) | ((unsigned)f2bf(b.y) << 16);
        o.w = (unsigned)f2bf(b.z) | ((unsigned)f2bf(b.w) << 16);
        *reinterpret_cast<uint4*>(xb + (size_t)i) = o;
        unsigned short q0 = f2fp8x2(a.x, a.y);
        unsigned short q1 = f2fp8x2(a.z, a.w);
        unsigned short q2 = f2fp8x2(b.x, b.y);
        unsigned short q3 = f2fp8x2(b.z, b.w);
        uint2 qo;
        qo.x = (unsigned)q0 | ((unsigned)q1 << 16);
        qo.y = (unsigned)q2 | ((unsigned)q3 << 16);
        *reinterpret_cast<uint2*>(xq + (size_t)i) = qo;
    } else if (bid < PREP_W1) {
        // B-frag: lane holds B[k=(lane>>4)*8+j][col=ct*16+(lane&15)]
        int t = (bid - PREP_CONV) * 256 + tid;   // 4096 = 8kt * 8ct * 64
        int lane = t & 63;
        int ct = (t >> 6) & 7;
        int kt = t >> 9;
        int c  = ct * 16 + (lane & 15);
        int k0 = (kt & 3) * 32 + (lane >> 4) * 8;
        const float* W = (kt < 4) ? W1l : W1r;
        unsigned int o[4];
#pragma unroll
        for (int j = 0; j < 4; ++j) {
            unsigned int lo = f2bf(W[(size_t)(k0 + 2 * j) * DF + c]);
            unsigned int hi = f2bf(W[(size_t)(k0 + 2 * j + 1) * DF + c]);
            o[j] = lo | (hi << 16);
        }
        uint4 v; v.x = o[0]; v.y = o[1]; v.z = o[2]; v.w = o[3];
        *reinterpret_cast<uint4*>(w1p + (size_t)t * 8) = v;
    } else if (bid < PREP_W2) {
        int t = (bid - PREP_W1) * 256 + tid;     // 1536 = 2 * 4kt * 3ct * 64
        if (t < 1536) {
            int lane = t & 63;
            int g  = t >> 6;       // 0..23
            int ct = g % 3;
            int kt = g / 3;        // <4 -> W2l else W2r
            int c  = ct * 16 + (lane & 15);
            int k0 = (kt & 3) * 32 + (lane >> 4) * 8;
            const float* W = (kt < 4) ? W2l : W2r;
            unsigned short* dstp = (kt < 4) ? w2lp : w2rp;
            int slot = ((kt & 3) * 3 + ct) * 64 + lane;
            unsigned int o[4];
#pragma unroll
            for (int j = 0; j < 4; ++j) {
                unsigned int lo = (c < DOUT) ? f2bf(W[(size_t)(k0 + 2 * j) * DOUT + c]) : 0u;
                unsigned int hi = (c < DOUT) ? f2bf(W[(size_t)(k0 + 2 * j + 1) * DOUT + c]) : 0u;
                o[j] = lo | (hi << 16);
            }
            uint4 v; v.x = o[0]; v.y = o[1]; v.z = o[2]; v.w = o[3];
            *reinterpret_cast<uint4*>(dstp + (size_t)slot * 8) = v;
        }
    } else {
        int i = (bid - PREP_W2) * 256 + tid;
        if (i < NN) deg[i] = 0;
    }
}

// ---------------- CSR build ----------------

__global__ __launch_bounds__(256) void hist_kernel(const int* __restrict__ dst,
                                                   int* __restrict__ deg,
                                                   int* __restrict__ rank) {
    int e = blockIdx.x * blockDim.x + threadIdx.x;
    if (e < NE) rank[e] = atomicAdd(&deg[dst[e]], 1);
}

__global__ __launch_bounds__(256) void scan_block_kernel(const int* __restrict__ deg,
                                                         int* __restrict__ loc,
                                                         int* __restrict__ part) {
    __shared__ int tmp[256];
    const int t = threadIdx.x;
    const int i = blockIdx.x * 256 + t;
    int v = (i < NN) ? deg[i] : 0;
    tmp[t] = v;
    __syncthreads();
    for (int off = 1; off < 256; off <<= 1) {
        int a = (t >= off) ? tmp[t - off] : 0;
        __syncthreads();
        tmp[t] += a;
        __syncthreads();
    }
    if (i < NN) loc[i] = tmp[t] - v;
    if (t == 255) part[blockIdx.x] = tmp[t];
}

__global__ __launch_bounds__(256) void add_off_kernel(const int* __restrict__ loc,
                                                      const int* __restrict__ part,
                                                      int* __restrict__ ofs) {
    __shared__ int wsum[4];
    const int bb = blockIdx.x;
    const int t  = threadIdx.x;
    int psum = 0;
    for (int i = t; i < bb; i += 256) psum += part[i];
#pragma unroll
    for (int off = 32; off > 0; off >>= 1) psum += __shfl_down(psum, off);
    if ((t & 63) == 0) wsum[t >> 6] = psum;
    __syncthreads();
    int base = wsum[0] + wsum[1] + wsum[2] + wsum[3];
    int i = bb * 256 + t;
    if (i < NN) ofs[i] = loc[i] + base;
    if (i == 0) ofs[NN] = NE;
}

__global__ __launch_bounds__(256) void fill_kernel(const int* __restrict__ src,
                                                   const int* __restrict__ dst,
                                                   const int* __restrict__ ofs,
                                                   const int* __restrict__ rank,
                                                   int* __restrict__ srcs) {
    int e = blockIdx.x * blockDim.x + threadIdx.x;
    if (e < NE) {
        int d = dst[e];
        srcs[ofs[d] + rank[e]] = src[e];
    }
}

// ---------------- gather-mean, 128-dim fp8 in -> bf16 out ------------------
// one wave per node; lane holds 2 fp8 of the 128-dim row; unroll-8 batches.
__global__ __launch_bounds__(256) void gather_mean_fp8_kernel(const unsigned char* __restrict__ xq,
                                                              const int* __restrict__ ofs,
                                                              const int* __restrict__ srcs,
                                                              unsigned short* __restrict__ agg) {
    const int gid  = blockIdx.x * 256 + threadIdx.x;
    const int node = gid >> 6;
    const int lane = threadIdx.x & 63;
    if (node >= NN) return;
    const int b = ofs[node];
    const int e = ofs[node + 1];
    const unsigned char* fp = xq + lane * 2;

    float ax0 = 0.f, ay0 = 0.f, ax1 = 0.f, ay1 = 0.f;
    float ax2 = 0.f, ay2 = 0.f, ax3 = 0.f, ay3 = 0.f;

    for (int j = b; j < e; j += 8) {
        int s[8];
#pragma unroll
        for (int k = 0; k < 8; ++k)
            s[k] = (j + k < e) ? srcs[j + k] : -1;
        unsigned short v[8];
#pragma unroll
        for (int k = 0; k < 8; ++k)
            v[k] = ((unsigned)s[k] < (unsigned)NN)
                 ? *reinterpret_cast<const unsigned short*>(fp + (size_t)s[k] * DF) : (unsigned short)0;
        float dx, dy;
        fp8pair(v[0], dx, dy); ax0 += dx; ay0 += dy;
        fp8pair(v[1], dx, dy); ax1 += dx; ay1 += dy;
        fp8pair(v[2], dx, dy); ax2 += dx; ay2 += dy;
        fp8pair(v[3], dx, dy); ax3 += dx; ay3 += dy;
        fp8pair(v[4], dx, dy); ax0 += dx; ay0 += dy;
        fp8pair(v[5], dx, dy); ax1 += dx; ay1 += dy;
        fp8pair(v[6], dx, dy); ax2 += dx; ay2 += dy;
        fp8pair(v[7], dx, dy); ax3 += dx; ay3 += dy;
    }

    float ax = (ax0 + ax1) + (ax2 + ax3);
    float ay = (ay0 + ay1) + (ay2 + ay3);
    const float sc = 1.0f / fmaxf((float)(e - b), 1.0f);
    unsigned int o = (unsigned)f2bf(ax * sc) | ((unsigned)f2bf(ay * sc) << 16);
    *reinterpret_cast<unsigned int*>(agg + (size_t)node * DF + lane * 2) = o;
}

// ---------------- gather-mean, 48-dim (h2 rows, bf16) ----------------------
__global__ __launch_bounds__(256) void gather_mean48_kernel(const unsigned short* __restrict__ feat,
                                                            const int* __restrict__ ofs,
                                                            const int* __restrict__ srcs,
                                                            unsigned short* __restrict__ agg) {
    const int gid  = blockIdx.x * 256 + threadIdx.x;
    const int node = gid >> 6;
    const int lane = threadIdx.x & 63;
    if (node >= NN) return;
    const int b = ofs[node];
    const int e = ofs[node + 1];
    const bool act = lane < 24;
    const unsigned short* fp = feat + lane * 2;

    float ax0 = 0.f, ay0 = 0.f, ax1 = 0.f, ay1 = 0.f;
    float ax2 = 0.f, ay2 = 0.f, ax3 = 0.f, ay3 = 0.f;

    for (int j = b; j < e; j += 8) {
        int s[8];
#pragma unroll
        for (int k = 0; k < 8; ++k)
            s[k] = (j + k < e) ? srcs[j + k] : -1;
        unsigned int v[8];
#pragma unroll
        for (int k = 0; k < 8; ++k)
            v[k] = (act && (unsigned)s[k] < (unsigned)NN)
                 ? *reinterpret_cast<const unsigned int*>(fp + (size_t)s[k] * D2) : 0u;
        ax0 += __uint_as_float(v[0] << 16);  ay0 += __uint_as_float(v[0] & 0xffff0000u);
        ax1 += __uint_as_float(v[1] << 16);  ay1 += __uint_as_float(v[1] & 0xffff0000u);
        ax2 += __uint_as_float(v[2] << 16);  ay2 += __uint_as_float(v[2] & 0xffff0000u);
        ax3 += __uint_as_float(v[3] << 16);  ay3 += __uint_as_float(v[3] & 0xffff0000u);
        ax0 += __uint_as_float(v[4] << 16);  ay0 += __uint_as_float(v[4] & 0xffff0000u);
        ax1 += __uint_as_float(v[5] << 16);  ay1 += __uint_as_float(v[5] & 0xffff0000u);
        ax2 += __uint_as_float(v[6] << 16);  ay2 += __uint_as_float(v[6] & 0xffff0000u);
        ax3 += __uint_as_float(v[7] << 16);  ay3 += __uint_as_float(v[7] & 0xffff0000u);
    }

    float ax = (ax0 + ax1) + (ax2 + ax3);
    float ay = (ay0 + ay1) + (ay2 + ay3);
    const float sc = 1.0f / fmaxf((float)(e - b), 1.0f);
    if (act) {
        unsigned int o = (unsigned)f2bf(ax * sc) | ((unsigned)f2bf(ay * sc) << 16);
        *reinterpret_cast<unsigned int*>(agg + (size_t)node * D2 + lane * 2) = o;
    }
}

// ---------------- MFMA GEMM (layer 1 + both layer-2 projections) -----------
// A-frag: lane holds A[row = lane&15][k = (lane>>4)*8 + j]
#define G_ROWS 64
#define LDSW 136

// stage 1: h = relu(agg@W1l + x@W1r + b1)  (registers only)
// stage 2: h2  = h @ W2l  -> [NN,48]  (for neighbor aggregation)
// stage 3: h2r = h @ W2r  -> [NN,48]  (self term; hb never materialized)
__global__ __launch_bounds__(256) void gemm1_kernel(const unsigned short* __restrict__ aggb,
                                                    const unsigned short* __restrict__ xb,
                                                    const unsigned short* __restrict__ w1p,
                                                    const unsigned short* __restrict__ w2lp,
                                                    const unsigned short* __restrict__ w2rp,
                                                    const float* __restrict__ b1,
                                                    unsigned short* __restrict__ h2b,
                                                    unsigned short* __restrict__ h2rb) {
    __shared__ unsigned short sA[G_ROWS * LDSW];
    __shared__ unsigned short sX[G_ROWS * LDSW];
    const int t = threadIdx.x;
    const int row0 = blockIdx.x * G_ROWS;

    for (int i = t; i < G_ROWS * 16; i += 256) {
        int r = i >> 4, ch = i & 15;
        int sr = row0 + r; if (sr > NN - 1) sr = NN - 1;
        *reinterpret_cast<uint4*>(&sA[r * LDSW + ch * 8]) =
            *reinterpret_cast<const uint4*>(aggb + (size_t)sr * DF + ch * 8);
        *reinterpret_cast<uint4*>(&sX[r * LDSW + ch * 8]) =
            *reinterpret_cast<const uint4*>(xb + (size_t)sr * DF + ch * 8);
    }
    __syncthreads();

    const int lane = t & 63;
    const int w = t >> 6;
    const int lr = lane & 15;
    const int hi = lane >> 4;
    f32x4 acc[8];
#pragma unroll
    for (int i = 0; i < 8; ++i) acc[i] = (f32x4){0.f, 0.f, 0.f, 0.f};

    const int arow = (w * 16 + lr) * LDSW + hi * 8;
#pragma unroll
    for (int half = 0; half < 2; ++half) {
        const unsigned short* base = half ? sX : sA;
#pragma unroll
        for (int kq = 0; kq < 4; ++kq) {
            bf16x8 a = __builtin_bit_cast(bf16x8,
                *reinterpret_cast<const uint4*>(&base[arow + kq * 32]));
            const unsigned short* wp = w1p + (size_t)(((half * 4 + kq) * 8) * 64 + lane) * 8;
#pragma unroll
            for (int ct = 0; ct < 8; ++ct) {
                bf16x8 b = __builtin_bit_cast(bf16x8,
                    *reinterpret_cast<const uint4*>(wp + ct * 512));
                acc[ct] = __builtin_amdgcn_mfma_f32_16x16x32_bf16(a, b, acc[ct], 0, 0, 0);
            }
        }
    }

    // relu + bias -> bf16 registers
    unsigned short hreg[8][4];
#pragma unroll
    for (int ct = 0; ct < 8; ++ct) {
        float bias = b1[ct * 16 + lr];
#pragma unroll
        for (int v = 0; v < 4; ++v) {
            hreg[ct][v] = f2bf(fmaxf(acc[ct][v] + bias, 0.f));
        }
    }

    __syncthreads();   // stage-1 LDS reads done before overwrite
#pragma unroll
    for (int ct = 0; ct < 8; ++ct) {
#pragma unroll
        for (int v = 0; v < 4; ++v) {
            sA[(w * 16 + hi * 4 + v) * LDSW + ct * 16 + lr] = hreg[ct][v];
        }
    }
    __syncthreads();

    // stages 2+3: h @ W2l and h @ W2r (48 padded cols each)
    f32x4 acc2[3], acc3[3];
#pragma unroll
    for (int i = 0; i < 3; ++i) {
        acc2[i] = (f32x4){0.f, 0.f, 0.f, 0.f};
        acc3[i] = (f32x4){0.f, 0.f, 0.f, 0.f};
    }
#pragma unroll
    for (int kq = 0; kq < 4; ++kq) {
        bf16x8 a = __builtin_bit_cast(bf16x8,
            *reinterpret_cast<const uint4*>(&sA[arow + kq * 32]));
        const unsigned short* wpl = w2lp + (size_t)((kq * 3) * 64 + lane) * 8;
        const unsigned short* wpr = w2rp + (size_t)((kq * 3) * 64 + lane) * 8;
#pragma unroll
        for (int ct = 0; ct < 3; ++ct) {
            bf16x8 bl = __builtin_bit_cast(bf16x8,
                *reinterpret_cast<const uint4*>(wpl + ct * 512));
            bf16x8 br = __builtin_bit_cast(bf16x8,
                *reinterpret_cast<const uint4*>(wpr + ct * 512));
            acc2[ct] = __builtin_amdgcn_mfma_f32_16x16x32_bf16(a, bl, acc2[ct], 0, 0, 0);
            acc3[ct] = __builtin_amdgcn_mfma_f32_16x16x32_bf16(a, br, acc3[ct], 0, 0, 0);
        }
    }
#pragma unroll
    for (int ct = 0; ct < 3; ++ct) {
        int col = ct * 16 + lr;
#pragma unroll
        for (int v = 0; v < 4; ++v) {
            int row = row0 + w * 16 + hi * 4 + v;
            if (row < NN) {
                h2b[(size_t)row * D2 + col]  = f2bf(acc2[ct][v]);
                h2rb[(size_t)row * D2 + col] = f2bf(acc3[ct][v]);
            }
        }
    }
}

// out = log_softmax( agg2 + h2r + b2 ),  [NN,40] — one wave per row
__global__ __launch_bounds__(256) void finish_kernel(const unsigned short* __restrict__ agg2b,
                                                     const unsigned short* __restrict__ h2rb,
                                                     const float* __restrict__ b2,
                                                     float* __restrict__ out) {
    const int gid  = blockIdx.x * 256 + threadIdx.x;
    const int node = gid >> 6;
    const int lane = threadIdx.x & 63;
    if (node >= NN) return;

    float lv = 0.f, v = -INFINITY;
    if (lane < DOUT) {
        lv = bf2f(agg2b[(size_t)node * D2 + lane]) +
             bf2f(h2rb[(size_t)node * D2 + lane]) + b2[lane];
        v = lv;
    }
    float mx = v;
#pragma unroll
    for (int off = 32; off > 0; off >>= 1) mx = fmaxf(mx, __shfl_xor(mx, off));
    float e = (lane < DOUT) ? __expf(lv - mx) : 0.f;
    float s = e;
#pragma unroll
    for (int off = 32; off > 0; off >>= 1) s += __shfl_xor(s, off);
    if (lane < DOUT) out[(size_t)node * DOUT + lane] = lv - mx - __logf(s);
}

extern "C" void kernel_launch(void* const* d_in, const int* in_sizes, int n_in,
                              void* d_out, int out_size, void* d_ws, size_t ws_size,
                              hipStream_t stream) {
    const float* x   = (const float*)d_in[0];
    const int*   ei  = (const int*)d_in[1];
    const int*   src = ei;
    const int*   dst = ei + NE;
    const float* W1l = (const float*)d_in[2];
    const float* W1r = (const float*)d_in[3];
    const float* b1  = (const float*)d_in[4];
    const float* W2l = (const float*)d_in[5];
    const float* W2r = (const float*)d_in[6];
    const float* b2  = (const float*)d_in[7];
    float* out = (float*)d_out;

    int* ip    = (int*)d_ws;
    int* deg   = ip;              // 100000
    int* loc   = ip + 100000;     // 100000
    int* ofs   = ip + 200000;     // 100004
    int* rank  = ip + 300004;     // 640000
    int* srcs  = ip + 940004;     // 640008
    int* part  = ip + 1580012;    // 512
    unsigned short* up    = (unsigned short*)(ip + 1580524);  // 16B aligned
    unsigned short* xb    = up;                   // NN*DF       = 12,800,000
    unsigned short* aggb  = up + 12800000;        // NN*DF
    unsigned short* h2b   = up + 25600000;        // NN*48       =  4,800,000
    unsigned short* h2rb  = up + 30400000;        // NN*48
    unsigned short* agg2b = up + 35200000;        // NN*48
    unsigned short* w1p   = up + 40000000;        // 32768
    unsigned short* w2lp  = up + 40032768;        // 6144
    unsigned short* w2rp  = up + 40038912;        // 6144
    unsigned char*  xq    = (unsigned char*)(up + 40045056);  // NN*DF bytes, 8B aligned

    prep_kernel<<<PREP_GRID, 256, 0, stream>>>(x, xb, xq, W1l, W1r, w1p,
                                               W2l, W2r, w2lp, w2rp, deg);

    hist_kernel<<<(NE + 255) / 256, 256, 0, stream>>>(dst, deg, rank);
    scan_block_kernel<<<391, 256, 0, stream>>>(deg, loc, part);
    add_off_kernel<<<391, 256, 0, stream>>>(loc, part, ofs);
    fill_kernel<<<(NE + 255) / 256, 256, 0, stream>>>(src, dst, ofs, rank, srcs);

    gather_mean_fp8_kernel<<<25000, 256, 0, stream>>>(xq, ofs, srcs, aggb);
    gemm1_kernel<<<1563, 256, 0, stream>>>(aggb, xb, w1p, w2lp, w2rp, b1, h2b, h2rb);
    gather_mean48_kernel<<<25000, 256, 0, stream>>>(h2b, ofs, srcs, agg2b);
    finish_kernel<<<25000, 256, 0, stream>>>(agg2b, h2rb, b2, out);
}

// Round 11
// 168.508 us; speedup vs baseline: 16.3288x; 1.0444x over previous
//
#include <hip/hip_runtime.h>
#include <math.h>

#define NN 100000   // nodes
#define NE 640000   // edges
#define DF 128      // in/hidden feat
#define DOUT 40     // out feat
#define D2 48       // padded W2 cols

typedef short bf16x8 __attribute__((ext_vector_type(8)));
typedef float f32x4 __attribute__((ext_vector_type(4)));
typedef float f32x2 __attribute__((ext_vector_type(2)));

#if defined(__has_builtin)
#if __has_builtin(__builtin_amdgcn_cvt_pk_f32_fp8) && __has_builtin(__builtin_amdgcn_cvt_pk_fp8_f32)
#define HW_FP8 1
#endif
#endif
#ifndef HW_FP8
#define HW_FP8 0
#endif

__device__ __forceinline__ unsigned short f2bf(float f) {
    unsigned int u = __float_as_uint(f);
    u += 0x7fffu + ((u >> 16) & 1u);   // RNE
    return (unsigned short)(u >> 16);
}
__device__ __forceinline__ float bf2f(unsigned short u) {
    return __uint_as_float((unsigned int)u << 16);
}

__device__ __forceinline__ unsigned int f2fp8_manual(float f) {
    unsigned u = __float_as_uint(f);
    unsigned s = (u >> 24) & 0x80u;
    unsigned au = u & 0x7fffffffu;
    if (au > 0x43e00000u) au = 0x43e00000u;   // clamp |x| to 448
    au += 0x7ffffu + ((au >> 20) & 1u);       // RNE to 3-bit mantissa
    if (au < 0x3c800000u) return s;           // flush < 2^-6 to 0
    unsigned e = (au >> 23) - 120u;
    return s | (e << 3) | ((au >> 20) & 7u);
}

__device__ __forceinline__ unsigned short f2fp8x2(float x, float y) {
#if HW_FP8
    int v = __builtin_amdgcn_cvt_pk_fp8_f32(x, y, 0, false);
    return (unsigned short)(v & 0xffff);
#else
    return (unsigned short)(f2fp8_manual(x) | (f2fp8_manual(y) << 8));
#endif
}

__device__ __forceinline__ void fp8pair(unsigned short p, float& x, float& y) {
#if HW_FP8
    f32x2 r = __builtin_amdgcn_cvt_pk_f32_fp8((int)(unsigned)p, false);
    x = r.x; y = r.y;
#else
    unsigned lo = p & 0xffu, hi = (p >> 8) & 0xffu;
    x = __uint_as_float(((lo & 0x80u) << 24) | ((lo & 0x7fu) << 20)) * 0x1.0p120f;
    y = __uint_as_float(((hi & 0x80u) << 24) | ((hi & 0x7fu) << 20)) * 0x1.0p120f;
#endif
}

// ---------------- fused prep: convert x (bf16 + fp8), pack W1/W2, zero deg --
#define PREP_CONV 6250
#define PREP_W1   (PREP_CONV + 16)
#define PREP_W2   (PREP_W1 + 6)
#define PREP_GRID (PREP_W2 + 391)

__global__ __launch_bounds__(256) void prep_kernel(const float* __restrict__ x,
                                                   unsigned short* __restrict__ xb,
                                                   unsigned char* __restrict__ xq,
                                                   const float* __restrict__ W1l,
                                                   const float* __restrict__ W1r,
                                                   unsigned short* __restrict__ w1p,
                                                   const float* __restrict__ W2l,
                                                   const float* __restrict__ W2r,
                                                   unsigned short* __restrict__ w2lp,
                                                   unsigned short* __restrict__ w2rp,
                                                   int* __restrict__ deg) {
    const int bid = blockIdx.x;
    const int tid = threadIdx.x;
    if (bid < PREP_CONV) {
        int i = (bid * 256 + tid) * 8;
        float4 a = *reinterpret_cast<const float4*>(x + i);
        float4 b = *reinterpret_cast<const float4*>(x + i + 4);
        uint4 o;
        o.x = (unsigned)f2bf(a.x) | ((unsigned)f2bf(a.y) << 16);
        o.y = (unsigned)f2bf(a.z) | ((unsigned)f2bf(a.w) << 16);
        o.z = (unsigned)f2bf(b.x) | ((unsigned)f2bf(b.y) << 16);
        o.w = (unsigned)f2bf(b.z) | ((unsigned)f2bf(b.w) << 16);
        *reinterpret_cast<uint4*>(xb + (size_t)i) = o;
        unsigned short q0 = f2fp8x2(a.x, a.y);
        unsigned short q1 = f2fp8x2(a.z, a.w);
        unsigned short q2 = f2fp8x2(b.x, b.y);
        unsigned short q3 = f2fp8x2(b.z, b.w);
        uint2 qo;
        qo.x = (unsigned)q0 | ((unsigned)q1 << 16);
        qo.y = (unsigned)q2 | ((unsigned)q3 << 16);
        *reinterpret_cast<uint2*>(xq + (size_t)i) = qo;
    } else if (bid < PREP_W1) {
        // B-frag: lane holds B[k=(lane>>4)*8+j][col=ct*16+(lane&15)]
        int t = (bid - PREP_CONV) * 256 + tid;   // 4096 = 8kt * 8ct * 64
        int lane = t & 63;
        int ct = (t >> 6) & 7;
        int kt = t >> 9;
        int c  = ct * 16 + (lane & 15);
        int k0 = (kt & 3) * 32 + (lane >> 4) * 8;
        const float* W = (kt < 4) ? W1l : W1r;
        unsigned int o[4];
#pragma unroll
        for (int j = 0; j < 4; ++j) {
            unsigned int lo = f2bf(W[(size_t)(k0 + 2 * j) * DF + c]);
            unsigned int hi = f2bf(W[(size_t)(k0 + 2 * j + 1) * DF + c]);
            o[j] = lo | (hi << 16);
        }
        uint4 v; v.x = o[0]; v.y = o[1]; v.z = o[2]; v.w = o[3];
        *reinterpret_cast<uint4*>(w1p + (size_t)t * 8) = v;
    } else if (bid < PREP_W2) {
        int t = (bid - PREP_W1) * 256 + tid;     // 1536 = 2 * 4kt * 3ct * 64
        if (t < 1536) {
            int lane = t & 63;
            int g  = t >> 6;       // 0..23
            int ct = g % 3;
            int kt = g / 3;        // <4 -> W2l else W2r
            int c  = ct * 16 + (lane & 15);
            int k0 = (kt & 3) * 32 + (lane >> 4) * 8;
            const float* W = (kt < 4) ? W2l : W2r;
            unsigned short* dstp = (kt < 4) ? w2lp : w2rp;
            int slot = ((kt & 3) * 3 + ct) * 64 + lane;
            unsigned int o[4];
#pragma unroll
            for (int j = 0; j < 4; ++j) {
                unsigned int lo = (c < DOUT) ? f2bf(W[(size_t)(k0 + 2 * j) * DOUT + c]) : 0u;
                unsigned int hi = (c < DOUT) ? f2bf(W[(size_t)(k0 + 2 * j + 1) * DOUT + c]) : 0u;
                o[j] = lo | (hi << 16);
            }
            uint4 v; v.x = o[0]; v.y = o[1]; v.z = o[2]; v.w = o[3];
            *reinterpret_cast<uint4*>(dstp + (size_t)slot * 8) = v;
        }
    } else {
        int i = (bid - PREP_W2) * 256 + tid;
        if (i < NN) deg[i] = 0;
    }
}

// ---------------- CSR build ----------------

__global__ __launch_bounds__(256) void hist_kernel(const int* __restrict__ dst,
                                                   int* __restrict__ deg,
                                                   int* __restrict__ rank) {
    int e = blockIdx.x * blockDim.x + threadIdx.x;
    if (e < NE) rank[e] = atomicAdd(&deg[dst[e]], 1);
}

__global__ __launch_bounds__(256) void scan_block_kernel(const int* __restrict__ deg,
                                                         int* __restrict__ loc,
                                                         int* __restrict__ part) {
    __shared__ int tmp[256];
    const int t = threadIdx.x;
    const int i = blockIdx.x * 256 + t;
    int v = (i < NN) ? deg[i] : 0;
    tmp[t] = v;
    __syncthreads();
    for (int off = 1; off < 256; off <<= 1) {
        int a = (t >= off) ? tmp[t - off] : 0;
        __syncthreads();
        tmp[t] += a;
        __syncthreads();
    }
    if (i < NN) loc[i] = tmp[t] - v;
    if (t == 255) part[blockIdx.x] = tmp[t];
}

// fused small-scan + finalize: ofs2[i] = {start, start+deg}
__global__ __launch_bounds__(256) void add_off_kernel(const int* __restrict__ loc,
                                                      const int* __restrict__ part,
                                                      const int* __restrict__ deg,
                                                      int2* __restrict__ ofs2) {
    __shared__ int wsum[4];
    const int bb = blockIdx.x;
    const int t  = threadIdx.x;
    int psum = 0;
    for (int i = t; i < bb; i += 256) psum += part[i];
#pragma unroll
    for (int off = 32; off > 0; off >>= 1) psum += __shfl_down(psum, off);
    if ((t & 63) == 0) wsum[t >> 6] = psum;
    __syncthreads();
    int base = wsum[0] + wsum[1] + wsum[2] + wsum[3];
    int i = bb * 256 + t;
    if (i < NN) {
        int o = loc[i] + base;
        ofs2[i] = make_int2(o, o + deg[i]);
    }
}

__global__ __launch_bounds__(256) void fill_kernel(const int* __restrict__ src,
                                                   const int* __restrict__ dst,
                                                   const int2* __restrict__ ofs2,
                                                   const int* __restrict__ rank,
                                                   int* __restrict__ srcs) {
    int e = blockIdx.x * blockDim.x + threadIdx.x;
    if (e < NE) {
        int d = dst[e];
        srcs[ofs2[d].x + rank[e]] = src[e];
    }
}

// ---------------- gather-mean, 128-dim fp8 in -> bf16 out ------------------
// one wave per node; lane holds 2 fp8 of the 128-dim row; unroll-8 batches.
__global__ __launch_bounds__(256) void gather_mean_fp8_kernel(const unsigned char* __restrict__ xq,
                                                              const int2* __restrict__ ofs2,
                                                              const int* __restrict__ srcs,
                                                              unsigned short* __restrict__ agg) {
    const int gid  = blockIdx.x * 256 + threadIdx.x;
    const int node = gid >> 6;
    const int lane = threadIdx.x & 63;
    if (node >= NN) return;
    const int2 be = ofs2[node];
    const int b = be.x;
    const int e = be.y;
    const unsigned char* fp = xq + lane * 2;

    float ax0 = 0.f, ay0 = 0.f, ax1 = 0.f, ay1 = 0.f;
    float ax2 = 0.f, ay2 = 0.f, ax3 = 0.f, ay3 = 0.f;

    for (int j = b; j < e; j += 8) {
        int s[8];
#pragma unroll
        for (int k = 0; k < 8; ++k)
            s[k] = (j + k < e) ? srcs[j + k] : -1;
        unsigned short v[8];
#pragma unroll
        for (int k = 0; k < 8; ++k)
            v[k] = ((unsigned)s[k] < (unsigned)NN)
                 ? *reinterpret_cast<const unsigned short*>(fp + (size_t)s[k] * DF) : (unsigned short)0;
        float dx, dy;
        fp8pair(v[0], dx, dy); ax0 += dx; ay0 += dy;
        fp8pair(v[1], dx, dy); ax1 += dx; ay1 += dy;
        fp8pair(v[2], dx, dy); ax2 += dx; ay2 += dy;
        fp8pair(v[3], dx, dy); ax3 += dx; ay3 += dy;
        fp8pair(v[4], dx, dy); ax0 += dx; ay0 += dy;
        fp8pair(v[5], dx, dy); ax1 += dx; ay1 += dy;
        fp8pair(v[6], dx, dy); ax2 += dx; ay2 += dy;
        fp8pair(v[7], dx, dy); ax3 += dx; ay3 += dy;
    }

    float ax = (ax0 + ax1) + (ax2 + ax3);
    float ay = (ay0 + ay1) + (ay2 + ay3);
    const float sc = 1.0f / fmaxf((float)(e - b), 1.0f);
    unsigned int o = (unsigned)f2bf(ax * sc) | ((unsigned)f2bf(ay * sc) << 16);
    *reinterpret_cast<unsigned int*>(agg + (size_t)node * DF + lane * 2) = o;
}

// ---------------- MFMA GEMM (layer 1 + both layer-2 projections) -----------
// A-frag: lane holds A[row = lane&15][k = (lane>>4)*8 + j]
#define G_ROWS 64
#define LDSW 136

__global__ __launch_bounds__(256) void gemm1_kernel(const unsigned short* __restrict__ aggb,
                                                    const unsigned short* __restrict__ xb,
                                                    const unsigned short* __restrict__ w1p,
                                                    const unsigned short* __restrict__ w2lp,
                                                    const unsigned short* __restrict__ w2rp,
                                                    const float* __restrict__ b1,
                                                    unsigned short* __restrict__ h2b,
                                                    unsigned short* __restrict__ h2rb) {
    __shared__ unsigned short sA[G_ROWS * LDSW];
    __shared__ unsigned short sX[G_ROWS * LDSW];
    const int t = threadIdx.x;
    const int row0 = blockIdx.x * G_ROWS;

    for (int i = t; i < G_ROWS * 16; i += 256) {
        int r = i >> 4, ch = i & 15;
        int sr = row0 + r; if (sr > NN - 1) sr = NN - 1;
        *reinterpret_cast<uint4*>(&sA[r * LDSW + ch * 8]) =
            *reinterpret_cast<const uint4*>(aggb + (size_t)sr * DF + ch * 8);
        *reinterpret_cast<uint4*>(&sX[r * LDSW + ch * 8]) =
            *reinterpret_cast<const uint4*>(xb + (size_t)sr * DF + ch * 8);
    }
    __syncthreads();

    const int lane = t & 63;
    const int w = t >> 6;
    const int lr = lane & 15;
    const int hi = lane >> 4;
    f32x4 acc[8];
#pragma unroll
    for (int i = 0; i < 8; ++i) acc[i] = (f32x4){0.f, 0.f, 0.f, 0.f};

    const int arow = (w * 16 + lr) * LDSW + hi * 8;
#pragma unroll
    for (int half = 0; half < 2; ++half) {
        const unsigned short* base = half ? sX : sA;
#pragma unroll
        for (int kq = 0; kq < 4; ++kq) {
            bf16x8 a = __builtin_bit_cast(bf16x8,
                *reinterpret_cast<const uint4*>(&base[arow + kq * 32]));
            const unsigned short* wp = w1p + (size_t)(((half * 4 + kq) * 8) * 64 + lane) * 8;
#pragma unroll
            for (int ct = 0; ct < 8; ++ct) {
                bf16x8 b = __builtin_bit_cast(bf16x8,
                    *reinterpret_cast<const uint4*>(wp + ct * 512));
                acc[ct] = __builtin_amdgcn_mfma_f32_16x16x32_bf16(a, b, acc[ct], 0, 0, 0);
            }
        }
    }

    // relu + bias -> bf16 registers
    unsigned short hreg[8][4];
#pragma unroll
    for (int ct = 0; ct < 8; ++ct) {
        float bias = b1[ct * 16 + lr];
#pragma unroll
        for (int v = 0; v < 4; ++v) {
            hreg[ct][v] = f2bf(fmaxf(acc[ct][v] + bias, 0.f));
        }
    }

    __syncthreads();   // stage-1 LDS reads done before overwrite
#pragma unroll
    for (int ct = 0; ct < 8; ++ct) {
#pragma unroll
        for (int v = 0; v < 4; ++v) {
            sA[(w * 16 + hi * 4 + v) * LDSW + ct * 16 + lr] = hreg[ct][v];
        }
    }
    __syncthreads();

    // stages 2+3: h @ W2l and h @ W2r (48 padded cols each)
    f32x4 acc2[3], acc3[3];
#pragma unroll
    for (int i = 0; i < 3; ++i) {
        acc2[i] = (f32x4){0.f, 0.f, 0.f, 0.f};
        acc3[i] = (f32x4){0.f, 0.f, 0.f, 0.f};
    }
#pragma unroll
    for (int kq = 0; kq < 4; ++kq) {
        bf16x8 a = __builtin_bit_cast(bf16x8,
            *reinterpret_cast<const uint4*>(&sA[arow + kq * 32]));
        const unsigned short* wpl = w2lp + (size_t)((kq * 3) * 64 + lane) * 8;
        const unsigned short* wpr = w2rp + (size_t)((kq * 3) * 64 + lane) * 8;
#pragma unroll
        for (int ct = 0; ct < 3; ++ct) {
            bf16x8 bl = __builtin_bit_cast(bf16x8,
                *reinterpret_cast<const uint4*>(wpl + ct * 512));
            bf16x8 br = __builtin_bit_cast(bf16x8,
                *reinterpret_cast<const uint4*>(wpr + ct * 512));
            acc2[ct] = __builtin_amdgcn_mfma_f32_16x16x32_bf16(a, bl, acc2[ct], 0, 0, 0);
            acc3[ct] = __builtin_amdgcn_mfma_f32_16x16x32_bf16(a, br, acc3[ct], 0, 0, 0);
        }
    }
#pragma unroll
    for (int ct = 0; ct < 3; ++ct) {
        int col = ct * 16 + lr;
#pragma unroll
        for (int v = 0; v < 4; ++v) {
            int row = row0 + w * 16 + hi * 4 + v;
            if (row < NN) {
                h2b[(size_t)row * D2 + col]  = f2bf(acc2[ct][v]);
                h2rb[(size_t)row * D2 + col] = f2bf(acc3[ct][v]);
            }
        }
    }
}

// ---------------- fused gather48 + log_softmax ------------------------------
// one wave per node; lanes 0..19 hold cols {2l, 2l+1} of the 40 used cols.
// gathers mean of h2 rows, adds self term h2r + b2, softmaxes in-register.
__global__ __launch_bounds__(256) void gather_finish_kernel(const unsigned short* __restrict__ h2b,
                                                            const unsigned short* __restrict__ h2rb,
                                                            const int2* __restrict__ ofs2,
                                                            const int* __restrict__ srcs,
                                                            const float* __restrict__ b2,
                                                            float* __restrict__ out) {
    const int gid  = blockIdx.x * 256 + threadIdx.x;
    const int node = gid >> 6;
    const int lane = threadIdx.x & 63;
    if (node >= NN) return;
    const int2 be = ofs2[node];
    const int b = be.x;
    const int e = be.y;
    const bool act = lane < 20;
    const unsigned short* fp = h2b + lane * 2;

    float ax0 = 0.f, ay0 = 0.f, ax1 = 0.f, ay1 = 0.f;
    float ax2 = 0.f, ay2 = 0.f, ax3 = 0.f, ay3 = 0.f;

    for (int j = b; j < e; j += 8) {
        int s[8];
#pragma unroll
        for (int k = 0; k < 8; ++k)
            s[k] = (j + k < e) ? srcs[j + k] : -1;
        unsigned int v[8];
#pragma unroll
        for (int k = 0; k < 8; ++k)
            v[k] = (act && (unsigned)s[k] < (unsigned)NN)
                 ? *reinterpret_cast<const unsigned int*>(fp + (size_t)s[k] * D2) : 0u;
        ax0 += __uint_as_float(v[0] << 16);  ay0 += __uint_as_float(v[0] & 0xffff0000u);
        ax1 += __uint_as_float(v[1] << 16);  ay1 += __uint_as_float(v[1] & 0xffff0000u);
        ax2 += __uint_as_float(v[2] << 16);  ay2 += __uint_as_float(v[2] & 0xffff0000u);
        ax3 += __uint_as_float(v[3] << 16);  ay3 += __uint_as_float(v[3] & 0xffff0000u);
        ax0 += __uint_as_float(v[4] << 16);  ay0 += __uint_as_float(v[4] & 0xffff0000u);
        ax1 += __uint_as_float(v[5] << 16);  ay1 += __uint_as_float(v[5] & 0xffff0000u);
        ax2 += __uint_as_float(v[6] << 16);  ay2 += __uint_as_float(v[6] & 0xffff0000u);
        ax3 += __uint_as_float(v[7] << 16);  ay3 += __uint_as_float(v[7] & 0xffff0000u);
    }

    const float sc = 1.0f / fmaxf((float)(e - b), 1.0f);
    float a0 = ((ax0 + ax1) + (ax2 + ax3)) * sc;
    float a1 = ((ay0 + ay1) + (ay2 + ay3)) * sc;

    float lv0 = -INFINITY, lv1 = -INFINITY;
    if (act) {
        unsigned int sv = *reinterpret_cast<const unsigned int*>(h2rb + (size_t)node * D2 + lane * 2);
        lv0 = a0 + __uint_as_float(sv << 16)        + b2[lane * 2];
        lv1 = a1 + __uint_as_float(sv & 0xffff0000u) + b2[lane * 2 + 1];
    }

    float mx = fmaxf(lv0, lv1);
#pragma unroll
    for (int off = 32; off > 0; off >>= 1) mx = fmaxf(mx, __shfl_xor(mx, off));
    float e0 = act ? __expf(lv0 - mx) : 0.f;
    float e1 = act ? __expf(lv1 - mx) : 0.f;
    float s = e0 + e1;
#pragma unroll
    for (int off = 32; off > 0; off >>= 1) s += __shfl_xor(s, off);
    float lz = mx + __logf(s);
    if (act) {
        float2 o = make_float2(lv0 - lz, lv1 - lz);
        *reinterpret_cast<float2*>(out + (size_t)node * DOUT + lane * 2) = o;
    }
}

extern "C" void kernel_launch(void* const* d_in, const int* in_sizes, int n_in,
                              void* d_out, int out_size, void* d_ws, size_t ws_size,
                              hipStream_t stream) {
    const float* x   = (const float*)d_in[0];
    const int*   ei  = (const int*)d_in[1];
    const int*   src = ei;
    const int*   dst = ei + NE;
    const float* W1l = (const float*)d_in[2];
    const float* W1r = (const float*)d_in[3];
    const float* b1  = (const float*)d_in[4];
    const float* W2l = (const float*)d_in[5];
    const float* W2r = (const float*)d_in[6];
    const float* b2  = (const float*)d_in[7];
    float* out = (float*)d_out;

    int* ip    = (int*)d_ws;
    int* deg   = ip;              // 100000
    int* loc   = ip + 100000;     // 100000
    int* rank  = ip + 200000;     // 640000
    int* srcs  = ip + 840000;     // 640008
    int* part  = ip + 1480008;    // 512
    int2* ofs2 = (int2*)(ip + 1480520);  // 100000 int2, 8B aligned
    unsigned short* up    = (unsigned short*)(ip + 1680520);  // 16B aligned
    unsigned short* xb    = up;                   // NN*DF = 12,800,000
    unsigned short* aggb  = up + 12800000;        // NN*DF
    unsigned short* h2b   = up + 25600000;        // NN*48 = 4,800,000
    unsigned short* h2rb  = up + 30400000;        // NN*48
    unsigned short* w1p   = up + 35200000;        // 32768
    unsigned short* w2lp  = up + 35232768;        // 6144
    unsigned short* w2rp  = up + 35238912;        // 6144
    unsigned char*  xq    = (unsigned char*)(up + 35245056);  // NN*DF bytes

    prep_kernel<<<PREP_GRID, 256, 0, stream>>>(x, xb, xq, W1l, W1r, w1p,
                                               W2l, W2r, w2lp, w2rp, deg);

    hist_kernel<<<(NE + 255) / 256, 256, 0, stream>>>(dst, deg, rank);
    scan_block_kernel<<<391, 256, 0, stream>>>(deg, loc, part);
    add_off_kernel<<<391, 256, 0, stream>>>(loc, part, deg, ofs2);
    fill_kernel<<<(NE + 255) / 256, 256, 0, stream>>>(src, dst, ofs2, rank, srcs);

    gather_mean_fp8_kernel<<<25000, 256, 0, stream>>>(xq, ofs2, srcs, aggb);
    gemm1_kernel<<<1563, 256, 0, stream>>>(aggb, xb, w1p, w2lp, w2rp, b1, h2b, h2rb);
    gather_finish_kernel<<<25000, 256, 0, stream>>>(h2b, h2rb, ofs2, srcs, b2, out);
}

// Round 12
// 153.553 us; speedup vs baseline: 17.9191x; 1.0974x over previous
//
#include <hip/hip_runtime.h>
#include <math.h>

#define NN 100000   // nodes
#define NE 640000   // edges
#define DF 128      // in/hidden feat
#define DOUT 40     // out feat
#define D2 48       // padded W2 cols

typedef short bf16x8 __attribute__((ext_vector_type(8)));
typedef float f32x4 __attribute__((ext_vector_type(4)));
typedef float f32x2 __attribute__((ext_vector_type(2)));

#if defined(__has_builtin)
#if __has_builtin(__builtin_amdgcn_cvt_pk_f32_fp8) && __has_builtin(__builtin_amdgcn_cvt_pk_fp8_f32)
#define HW_FP8 1
#endif
#endif
#ifndef HW_FP8
#define HW_FP8 0
#endif

__device__ __forceinline__ unsigned short f2bf(float f) {
    unsigned int u = __float_as_uint(f);
    u += 0x7fffu + ((u >> 16) & 1u);   // RNE
    return (unsigned short)(u >> 16);
}
__device__ __forceinline__ float bf2f(unsigned short u) {
    return __uint_as_float((unsigned int)u << 16);
}

__device__ __forceinline__ unsigned int f2fp8_manual(float f) {
    unsigned u = __float_as_uint(f);
    unsigned s = (u >> 24) & 0x80u;
    unsigned au = u & 0x7fffffffu;
    if (au > 0x43e00000u) au = 0x43e00000u;   // clamp |x| to 448
    au += 0x7ffffu + ((au >> 20) & 1u);       // RNE to 3-bit mantissa
    if (au < 0x3c800000u) return s;           // flush < 2^-6 to 0
    unsigned e = (au >> 23) - 120u;
    return s | (e << 3) | ((au >> 20) & 7u);
}

__device__ __forceinline__ unsigned short f2fp8x2(float x, float y) {
#if HW_FP8
    int v = __builtin_amdgcn_cvt_pk_fp8_f32(x, y, 0, false);
    return (unsigned short)(v & 0xffff);
#else
    return (unsigned short)(f2fp8_manual(x) | (f2fp8_manual(y) << 8));
#endif
}

__device__ __forceinline__ void fp8pair(unsigned short p, float& x, float& y) {
#if HW_FP8
    f32x2 r = __builtin_amdgcn_cvt_pk_f32_fp8((int)(unsigned)p, false);
    x = r.x; y = r.y;
#else
    unsigned lo = p & 0xffu, hi = (p >> 8) & 0xffu;
    x = __uint_as_float(((lo & 0x80u) << 24) | ((lo & 0x7fu) << 20)) * 0x1.0p120f;
    y = __uint_as_float(((hi & 0x80u) << 24) | ((hi & 0x7fu) << 20)) * 0x1.0p120f;
#endif
}

// ---------------- fused prep: convert x (bf16 + fp8), pack W1/W2, zero deg --
#define PREP_CONV 6250
#define PREP_W1   (PREP_CONV + 16)
#define PREP_W2   (PREP_W1 + 6)
#define PREP_GRID (PREP_W2 + 391)

__global__ __launch_bounds__(256) void prep_kernel(const float* __restrict__ x,
                                                   unsigned short* __restrict__ xb,
                                                   unsigned char* __restrict__ xq,
                                                   const float* __restrict__ W1l,
                                                   const float* __restrict__ W1r,
                                                   unsigned short* __restrict__ w1p,
                                                   const float* __restrict__ W2l,
                                                   const float* __restrict__ W2r,
                                                   unsigned short* __restrict__ w2lp,
                                                   unsigned short* __restrict__ w2rp,
                                                   int* __restrict__ deg) {
    const int bid = blockIdx.x;
    const int tid = threadIdx.x;
    if (bid < PREP_CONV) {
        int i = (bid * 256 + tid) * 8;
        float4 a = *reinterpret_cast<const float4*>(x + i);
        float4 b = *reinterpret_cast<const float4*>(x + i + 4);
        uint4 o;
        o.x = (unsigned)f2bf(a.x) | ((unsigned)f2bf(a.y) << 16);
        o.y = (unsigned)f2bf(a.z) | ((unsigned)f2bf(a.w) << 16);
        o.z = (unsigned)f2bf(b.x) | ((unsigned)f2bf(b.y) << 16);
        o.w = (unsigned)f2bf(b.z) | ((unsigned)f2bf(b.w) << 16);
        *reinterpret_cast<uint4*>(xb + (size_t)i) = o;
        unsigned short q0 = f2fp8x2(a.x, a.y);
        unsigned short q1 = f2fp8x2(a.z, a.w);
        unsigned short q2 = f2fp8x2(b.x, b.y);
        unsigned short q3 = f2fp8x2(b.z, b.w);
        uint2 qo;
        qo.x = (unsigned)q0 | ((unsigned)q1 << 16);
        qo.y = (unsigned)q2 | ((unsigned)q3 << 16);
        *reinterpret_cast<uint2*>(xq + (size_t)i) = qo;
    } else if (bid < PREP_W1) {
        // B-frag: lane holds B[k=(lane>>4)*8+j][col=ct*16+(lane&15)]
        int t = (bid - PREP_CONV) * 256 + tid;   // 4096 = 8kt * 8ct * 64
        int lane = t & 63;
        int ct = (t >> 6) & 7;
        int kt = t >> 9;
        int c  = ct * 16 + (lane & 15);
        int k0 = (kt & 3) * 32 + (lane >> 4) * 8;
        const float* W = (kt < 4) ? W1l : W1r;
        unsigned int o[4];
#pragma unroll
        for (int j = 0; j < 4; ++j) {
            unsigned int lo = f2bf(W[(size_t)(k0 + 2 * j) * DF + c]);
            unsigned int hi = f2bf(W[(size_t)(k0 + 2 * j + 1) * DF + c]);
            o[j] = lo | (hi << 16);
        }
        uint4 v; v.x = o[0]; v.y = o[1]; v.z = o[2]; v.w = o[3];
        *reinterpret_cast<uint4*>(w1p + (size_t)t * 8) = v;
    } else if (bid < PREP_W2) {
        int t = (bid - PREP_W1) * 256 + tid;     // 1536 = 2 * 4kt * 3ct * 64
        if (t < 1536) {
            int lane = t & 63;
            int g  = t >> 6;       // 0..23
            int ct = g % 3;
            int kt = g / 3;        // <4 -> W2l else W2r
            int c  = ct * 16 + (lane & 15);
            int k0 = (kt & 3) * 32 + (lane >> 4) * 8;
            const float* W = (kt < 4) ? W2l : W2r;
            unsigned short* dstp = (kt < 4) ? w2lp : w2rp;
            int slot = ((kt & 3) * 3 + ct) * 64 + lane;
            unsigned int o[4];
#pragma unroll
            for (int j = 0; j < 4; ++j) {
                unsigned int lo = (c < DOUT) ? f2bf(W[(size_t)(k0 + 2 * j) * DOUT + c]) : 0u;
                unsigned int hi = (c < DOUT) ? f2bf(W[(size_t)(k0 + 2 * j + 1) * DOUT + c]) : 0u;
                o[j] = lo | (hi << 16);
            }
            uint4 v; v.x = o[0]; v.y = o[1]; v.z = o[2]; v.w = o[3];
            *reinterpret_cast<uint4*>(dstp + (size_t)slot * 8) = v;
        }
    } else {
        int i = (bid - PREP_W2) * 256 + tid;
        if (i < NN) deg[i] = 0;
    }
}

// ---------------- CSR build ----------------

__global__ __launch_bounds__(256) void hist_kernel(const int* __restrict__ dst,
                                                   int* __restrict__ deg,
                                                   int* __restrict__ rank) {
    int e = blockIdx.x * blockDim.x + threadIdx.x;
    if (e < NE) rank[e] = atomicAdd(&deg[dst[e]], 1);
}

__global__ __launch_bounds__(256) void scan_block_kernel(const int* __restrict__ deg,
                                                         int* __restrict__ loc,
                                                         int* __restrict__ part) {
    __shared__ int tmp[256];
    const int t = threadIdx.x;
    const int i = blockIdx.x * 256 + t;
    int v = (i < NN) ? deg[i] : 0;
    tmp[t] = v;
    __syncthreads();
    for (int off = 1; off < 256; off <<= 1) {
        int a = (t >= off) ? tmp[t - off] : 0;
        __syncthreads();
        tmp[t] += a;
        __syncthreads();
    }
    if (i < NN) loc[i] = tmp[t] - v;
    if (t == 255) part[blockIdx.x] = tmp[t];
}

// fused small-scan + finalize: ofs2[i] = {start, start+deg}
__global__ __launch_bounds__(256) void add_off_kernel(const int* __restrict__ loc,
                                                      const int* __restrict__ part,
                                                      const int* __restrict__ deg,
                                                      int2* __restrict__ ofs2) {
    __shared__ int wsum[4];
    const int bb = blockIdx.x;
    const int t  = threadIdx.x;
    int psum = 0;
    for (int i = t; i < bb; i += 256) psum += part[i];
#pragma unroll
    for (int off = 32; off > 0; off >>= 1) psum += __shfl_down(psum, off);
    if ((t & 63) == 0) wsum[t >> 6] = psum;
    __syncthreads();
    int base = wsum[0] + wsum[1] + wsum[2] + wsum[3];
    int i = bb * 256 + t;
    if (i < NN) {
        int o = loc[i] + base;
        ofs2[i] = make_int2(o, o + deg[i]);
    }
}

__global__ __launch_bounds__(256) void fill_kernel(const int* __restrict__ src,
                                                   const int* __restrict__ dst,
                                                   const int2* __restrict__ ofs2,
                                                   const int* __restrict__ rank,
                                                   int* __restrict__ srcs) {
    int e = blockIdx.x * blockDim.x + threadIdx.x;
    if (e < NE) {
        int d = dst[e];
        srcs[ofs2[d].x + rank[e]] = src[e];
    }
}

// ---------------- gather-mean, 128-dim fp8 in -> bf16 out ------------------
// one wave per node; lane holds 2 fp8 of the 128-dim row; unroll-8 batches.
__global__ __launch_bounds__(256) void gather_mean_fp8_kernel(const unsigned char* __restrict__ xq,
                                                              const int2* __restrict__ ofs2,
                                                              const int* __restrict__ srcs,
                                                              unsigned short* __restrict__ agg) {
    const int gid  = blockIdx.x * 256 + threadIdx.x;
    const int node = gid >> 6;
    const int lane = threadIdx.x & 63;
    if (node >= NN) return;
    const int2 be = ofs2[node];
    const int b = be.x;
    const int e = be.y;
    const unsigned char* fp = xq + lane * 2;

    float ax0 = 0.f, ay0 = 0.f, ax1 = 0.f, ay1 = 0.f;
    float ax2 = 0.f, ay2 = 0.f, ax3 = 0.f, ay3 = 0.f;

    for (int j = b; j < e; j += 8) {
        int s[8];
#pragma unroll
        for (int k = 0; k < 8; ++k)
            s[k] = (j + k < e) ? srcs[j + k] : -1;
        unsigned short v[8];
#pragma unroll
        for (int k = 0; k < 8; ++k)
            v[k] = ((unsigned)s[k] < (unsigned)NN)
                 ? *reinterpret_cast<const unsigned short*>(fp + (size_t)s[k] * DF) : (unsigned short)0;
        float dx, dy;
        fp8pair(v[0], dx, dy); ax0 += dx; ay0 += dy;
        fp8pair(v[1], dx, dy); ax1 += dx; ay1 += dy;
        fp8pair(v[2], dx, dy); ax2 += dx; ay2 += dy;
        fp8pair(v[3], dx, dy); ax3 += dx; ay3 += dy;
        fp8pair(v[4], dx, dy); ax0 += dx; ay0 += dy;
        fp8pair(v[5], dx, dy); ax1 += dx; ay1 += dy;
        fp8pair(v[6], dx, dy); ax2 += dx; ay2 += dy;
        fp8pair(v[7], dx, dy); ax3 += dx; ay3 += dy;
    }

    float ax = (ax0 + ax1) + (ax2 + ax3);
    float ay = (ay0 + ay1) + (ay2 + ay3);
    const float sc = 1.0f / fmaxf((float)(e - b), 1.0f);
    unsigned int o = (unsigned)f2bf(ax * sc) | ((unsigned)f2bf(ay * sc) << 16);
    *reinterpret_cast<unsigned int*>(agg + (size_t)node * DF + lane * 2) = o;
}

// ---------------- MFMA GEMM (layer 1 + both layer-2 projections) -----------
// A-frag: lane holds A[row = lane&15][k = (lane>>4)*8 + j]
#define G_ROWS 64
#define LDSW 136

__global__ __launch_bounds__(256) void gemm1_kernel(const unsigned short* __restrict__ aggb,
                                                    const unsigned short* __restrict__ xb,
                                                    const unsigned short* __restrict__ w1p,
                                                    const unsigned short* __restrict__ w2lp,
                                                    const unsigned short* __restrict__ w2rp,
                                                    const float* __restrict__ b1,
                                                    const float* __restrict__ b2,
                                                    unsigned short* __restrict__ h2b,
                                                    unsigned short* __restrict__ h2rb) {
    __shared__ unsigned short sA[G_ROWS * LDSW];
    __shared__ unsigned short sX[G_ROWS * LDSW];
    const int t = threadIdx.x;
    const int row0 = blockIdx.x * G_ROWS;

    for (int i = t; i < G_ROWS * 16; i += 256) {
        int r = i >> 4, ch = i & 15;
        int sr = row0 + r; if (sr > NN - 1) sr = NN - 1;
        *reinterpret_cast<uint4*>(&sA[r * LDSW + ch * 8]) =
            *reinterpret_cast<const uint4*>(aggb + (size_t)sr * DF + ch * 8);
        *reinterpret_cast<uint4*>(&sX[r * LDSW + ch * 8]) =
            *reinterpret_cast<const uint4*>(xb + (size_t)sr * DF + ch * 8);
    }
    __syncthreads();

    const int lane = t & 63;
    const int w = t >> 6;
    const int lr = lane & 15;
    const int hi = lane >> 4;
    f32x4 acc[8];
#pragma unroll
    for (int i = 0; i < 8; ++i) acc[i] = (f32x4){0.f, 0.f, 0.f, 0.f};

    const int arow = (w * 16 + lr) * LDSW + hi * 8;
#pragma unroll
    for (int half = 0; half < 2; ++half) {
        const unsigned short* base = half ? sX : sA;
#pragma unroll
        for (int kq = 0; kq < 4; ++kq) {
            bf16x8 a = __builtin_bit_cast(bf16x8,
                *reinterpret_cast<const uint4*>(&base[arow + kq * 32]));
            const unsigned short* wp = w1p + (size_t)(((half * 4 + kq) * 8) * 64 + lane) * 8;
#pragma unroll
            for (int ct = 0; ct < 8; ++ct) {
                bf16x8 b = __builtin_bit_cast(bf16x8,
                    *reinterpret_cast<const uint4*>(wp + ct * 512));
                acc[ct] = __builtin_amdgcn_mfma_f32_16x16x32_bf16(a, b, acc[ct], 0, 0, 0);
            }
        }
    }

    // relu + bias -> bf16 registers
    unsigned short hreg[8][4];
#pragma unroll
    for (int ct = 0; ct < 8; ++ct) {
        float bias = b1[ct * 16 + lr];
#pragma unroll
        for (int v = 0; v < 4; ++v) {
            hreg[ct][v] = f2bf(fmaxf(acc[ct][v] + bias, 0.f));
        }
    }

    __syncthreads();   // stage-1 LDS reads done before overwrite
#pragma unroll
    for (int ct = 0; ct < 8; ++ct) {
#pragma unroll
        for (int v = 0; v < 4; ++v) {
            sA[(w * 16 + hi * 4 + v) * LDSW + ct * 16 + lr] = hreg[ct][v];
        }
    }
    __syncthreads();

    // stages 2+3: h @ W2l and h @ W2r + b2 (48 padded cols each)
    f32x4 acc2[3], acc3[3];
#pragma unroll
    for (int i = 0; i < 3; ++i) {
        acc2[i] = (f32x4){0.f, 0.f, 0.f, 0.f};
        acc3[i] = (f32x4){0.f, 0.f, 0.f, 0.f};
    }
#pragma unroll
    for (int kq = 0; kq < 4; ++kq) {
        bf16x8 a = __builtin_bit_cast(bf16x8,
            *reinterpret_cast<const uint4*>(&sA[arow + kq * 32]));
        const unsigned short* wpl = w2lp + (size_t)((kq * 3) * 64 + lane) * 8;
        const unsigned short* wpr = w2rp + (size_t)((kq * 3) * 64 + lane) * 8;
#pragma unroll
        for (int ct = 0; ct < 3; ++ct) {
            bf16x8 bl = __builtin_bit_cast(bf16x8,
                *reinterpret_cast<const uint4*>(wpl + ct * 512));
            bf16x8 br = __builtin_bit_cast(bf16x8,
                *reinterpret_cast<const uint4*>(wpr + ct * 512));
            acc2[ct] = __builtin_amdgcn_mfma_f32_16x16x32_bf16(a, bl, acc2[ct], 0, 0, 0);
            acc3[ct] = __builtin_amdgcn_mfma_f32_16x16x32_bf16(a, br, acc3[ct], 0, 0, 0);
        }
    }
#pragma unroll
    for (int ct = 0; ct < 3; ++ct) {
        int col = ct * 16 + lr;
        float bias2 = (col < DOUT) ? b2[col] : 0.f;
#pragma unroll
        for (int v = 0; v < 4; ++v) {
            int row = row0 + w * 16 + hi * 4 + v;
            if (row < NN) {
                h2b[(size_t)row * D2 + col]  = f2bf(acc2[ct][v]);
                h2rb[(size_t)row * D2 + col] = f2bf(acc3[ct][v] + bias2);
            }
        }
    }
}

// ---------------- fused gather48 + log_softmax, 2 nodes per wave -----------
// each 32-lane half handles one node; lanes 0..19 of the half hold col pair
// {2l, 2l+1}. xor-shuffle reduce (offsets 16..1) stays within the half.
__global__ __launch_bounds__(256) void gather_finish_kernel(const unsigned short* __restrict__ h2b,
                                                            const unsigned short* __restrict__ h2rb,
                                                            const int2* __restrict__ ofs2,
                                                            const int* __restrict__ srcs,
                                                            float* __restrict__ out) {
    const int gid   = blockIdx.x * 256 + threadIdx.x;
    const int node  = gid >> 5;                 // 2 nodes per wave
    const int lane32 = threadIdx.x & 31;
    if (node >= NN) return;
    const int2 be = ofs2[node];
    const int b = be.x;
    const int e = be.y;
    const bool act = lane32 < 20;
    const unsigned short* fp = h2b + lane32 * 2;

    float ax0 = 0.f, ay0 = 0.f, ax1 = 0.f, ay1 = 0.f;
    float ax2 = 0.f, ay2 = 0.f, ax3 = 0.f, ay3 = 0.f;

    for (int j = b; j < e; j += 8) {
        int s[8];
#pragma unroll
        for (int k = 0; k < 8; ++k)
            s[k] = (j + k < e) ? srcs[j + k] : -1;
        unsigned int v[8];
#pragma unroll
        for (int k = 0; k < 8; ++k)
            v[k] = (act && (unsigned)s[k] < (unsigned)NN)
                 ? *reinterpret_cast<const unsigned int*>(fp + (size_t)s[k] * D2) : 0u;
        ax0 += __uint_as_float(v[0] << 16);  ay0 += __uint_as_float(v[0] & 0xffff0000u);
        ax1 += __uint_as_float(v[1] << 16);  ay1 += __uint_as_float(v[1] & 0xffff0000u);
        ax2 += __uint_as_float(v[2] << 16);  ay2 += __uint_as_float(v[2] & 0xffff0000u);
        ax3 += __uint_as_float(v[3] << 16);  ay3 += __uint_as_float(v[3] & 0xffff0000u);
        ax0 += __uint_as_float(v[4] << 16);  ay0 += __uint_as_float(v[4] & 0xffff0000u);
        ax1 += __uint_as_float(v[5] << 16);  ay1 += __uint_as_float(v[5] & 0xffff0000u);
        ax2 += __uint_as_float(v[6] << 16);  ay2 += __uint_as_float(v[6] & 0xffff0000u);
        ax3 += __uint_as_float(v[7] << 16);  ay3 += __uint_as_float(v[7] & 0xffff0000u);
    }

    const float sc = 1.0f / fmaxf((float)(e - b), 1.0f);
    float a0 = ((ax0 + ax1) + (ax2 + ax3)) * sc;
    float a1 = ((ay0 + ay1) + (ay2 + ay3)) * sc;

    float lv0 = -INFINITY, lv1 = -INFINITY;
    if (act) {
        unsigned int sv = *reinterpret_cast<const unsigned int*>(h2rb + (size_t)node * D2 + lane32 * 2);
        lv0 = a0 + __uint_as_float(sv << 16);
        lv1 = a1 + __uint_as_float(sv & 0xffff0000u);
    }

    float mx = fmaxf(lv0, lv1);
#pragma unroll
    for (int off = 16; off > 0; off >>= 1) mx = fmaxf(mx, __shfl_xor(mx, off));
    float e0 = act ? __expf(lv0 - mx) : 0.f;
    float e1 = act ? __expf(lv1 - mx) : 0.f;
    float s = e0 + e1;
#pragma unroll
    for (int off = 16; off > 0; off >>= 1) s += __shfl_xor(s, off);
    float lz = mx + __logf(s);
    if (act) {
        float2 o = make_float2(lv0 - lz, lv1 - lz);
        *reinterpret_cast<float2*>(out + (size_t)node * DOUT + lane32 * 2) = o;
    }
}

extern "C" void kernel_launch(void* const* d_in, const int* in_sizes, int n_in,
                              void* d_out, int out_size, void* d_ws, size_t ws_size,
                              hipStream_t stream) {
    const float* x   = (const float*)d_in[0];
    const int*   ei  = (const int*)d_in[1];
    const int*   src = ei;
    const int*   dst = ei + NE;
    const float* W1l = (const float*)d_in[2];
    const float* W1r = (const float*)d_in[3];
    const float* b1  = (const float*)d_in[4];
    const float* W2l = (const float*)d_in[5];
    const float* W2r = (const float*)d_in[6];
    const float* b2  = (const float*)d_in[7];
    float* out = (float*)d_out;

    int* ip    = (int*)d_ws;
    int* deg   = ip;              // 100000
    int* loc   = ip + 100000;     // 100000
    int* rank  = ip + 200000;     // 640000
    int* srcs  = ip + 840000;     // 640008
    int* part  = ip + 1480008;    // 512
    int2* ofs2 = (int2*)(ip + 1480520);  // 100000 int2, 8B aligned
    unsigned short* up    = (unsigned short*)(ip + 1680520);  // 16B aligned
    unsigned short* xb    = up;                   // NN*DF = 12,800,000
    unsigned short* aggb  = up + 12800000;        // NN*DF
    unsigned short* h2b   = up + 25600000;        // NN*48 = 4,800,000
    unsigned short* h2rb  = up + 30400000;        // NN*48
    unsigned short* w1p   = up + 35200000;        // 32768
    unsigned short* w2lp  = up + 35232768;        // 6144
    unsigned short* w2rp  = up + 35238912;        // 6144
    unsigned char*  xq    = (unsigned char*)(up + 35245056);  // NN*DF bytes

    prep_kernel<<<PREP_GRID, 256, 0, stream>>>(x, xb, xq, W1l, W1r, w1p,
                                               W2l, W2r, w2lp, w2rp, deg);

    hist_kernel<<<(NE + 255) / 256, 256, 0, stream>>>(dst, deg, rank);
    scan_block_kernel<<<391, 256, 0, stream>>>(deg, loc, part);
    add_off_kernel<<<391, 256, 0, stream>>>(loc, part, deg, ofs2);
    fill_kernel<<<(NE + 255) / 256, 256, 0, stream>>>(src, dst, ofs2, rank, srcs);

    gather_mean_fp8_kernel<<<25000, 256, 0, stream>>>(xq, ofs2, srcs, aggb);
    gemm1_kernel<<<1563, 256, 0, stream>>>(aggb, xb, w1p, w2lp, w2rp, b1, b2, h2b, h2rb);
    gather_finish_kernel<<<12500, 256, 0, stream>>>(h2b, h2rb, ofs2, srcs, out);
}